// Round 1
// baseline (620.502 us; speedup 1.0000x reference)
//
#include <hip/hip_runtime.h>
#include <cstdint>

// Transformer block: LN1 -> qkv GEMM -> flash attn -> out-proj(+res) -> LN2
// -> fc1(+GELU) -> fc2(+res). All matmuls bf16 MFMA (16x16x32), fp32 accum.

using short8 = __attribute__((ext_vector_type(8))) short;
using f32x4  = __attribute__((ext_vector_type(4))) float;

#define EMBED  1024
#define HIDDEN 4096
#define SEQ    2048
#define NTOK   8192   // 4*2048

__device__ __forceinline__ ushort f2bf(float x) {
  union { float f; uint32_t u; } v; v.f = x;
  uint32_t r = v.u + 0x7fffu + ((v.u >> 16) & 1u);   // RNE
  return (ushort)(r >> 16);
}

__device__ __forceinline__ void gload16(const void* g, void* l) {
  __builtin_amdgcn_global_load_lds((__attribute__((address_space(1))) void*)(g),
                                   (__attribute__((address_space(3))) void*)(l), 16, 0, 0);
}

__device__ __forceinline__ f32x4 mfma16(short8 a, short8 b, f32x4 c) {
  return __builtin_amdgcn_mfma_f32_16x16x32_bf16(a, b, c, 0, 0, 0);
}

// ---------------- fp32 -> bf16 weight conversion ----------------
__global__ __launch_bounds__(256) void cvt_bf16_kernel(const float* __restrict__ in,
                                                       ushort* __restrict__ out, int n4) {
  int i = blockIdx.x * 256 + threadIdx.x;
  if (i < n4) {
    float4 v = reinterpret_cast<const float4*>(in)[i];
    ushort4 o; o.x = f2bf(v.x); o.y = f2bf(v.y); o.z = f2bf(v.z); o.w = f2bf(v.w);
    reinterpret_cast<ushort4*>(out)[i] = o;
  }
}

// ---------------- LayerNorm (fp32 in, bf16 out) ----------------
__global__ __launch_bounds__(256) void ln_kernel(const float* __restrict__ x,
                                                 const float* __restrict__ g,
                                                 const float* __restrict__ b,
                                                 ushort* __restrict__ out) {
  const int row = blockIdx.x, tid = threadIdx.x;
  const float4 xv = reinterpret_cast<const float4*>(x + (size_t)row * EMBED)[tid];
  float s  = xv.x + xv.y + xv.z + xv.w;
  float s2 = xv.x*xv.x + xv.y*xv.y + xv.z*xv.z + xv.w*xv.w;
  #pragma unroll
  for (int off = 32; off >= 1; off >>= 1) { s += __shfl_xor(s, off); s2 += __shfl_xor(s2, off); }
  __shared__ float ps[4], ps2[4];
  if ((tid & 63) == 0) { ps[tid >> 6] = s; ps2[tid >> 6] = s2; }
  __syncthreads();
  s  = ps[0] + ps[1] + ps[2] + ps[3];
  s2 = ps2[0] + ps2[1] + ps2[2] + ps2[3];
  const float mu  = s * (1.f / EMBED);
  const float var = s2 * (1.f / EMBED) - mu * mu;
  const float rs  = rsqrtf(var + 1e-5f);
  const float4 gv = reinterpret_cast<const float4*>(g)[tid];
  const float4 bv = reinterpret_cast<const float4*>(b)[tid];
  ushort4 o;
  o.x = f2bf((xv.x - mu) * rs * gv.x + bv.x);
  o.y = f2bf((xv.y - mu) * rs * gv.y + bv.y);
  o.z = f2bf((xv.z - mu) * rs * gv.z + bv.z);
  o.w = f2bf((xv.w - mu) * rs * gv.w + bv.w);
  reinterpret_cast<ushort4*>(out + (size_t)row * EMBED)[tid] = o;
}

// ---------------- bf16 GEMM: C[M,N] = A[M,K] * B[N,K]^T (+epilogue) ----------------
// EPI 0: outb = bf16(acc)
// EPI 1: outf = acc + bias[col] + res[idx]      (fp32 out)
// EPI 2: outb = bf16(gelu_erf(acc + bias[col]))
template<int EPI>
__global__ __launch_bounds__(256) void gemm_bt(const ushort* __restrict__ A,
                                               const ushort* __restrict__ B,
                                               const float* __restrict__ bias,
                                               const float* __restrict__ res,
                                               ushort* __restrict__ outb,
                                               float* __restrict__ outf,
                                               int M, int N, int K) {
  __shared__ ushort sA[128 * 32];
  __shared__ ushort sB[128 * 32];
  const int tid = threadIdx.x, lane = tid & 63, wave = tid >> 6;
  const int m0 = blockIdx.x * 128, n0 = blockIdx.y * 128;
  const int wm = (wave >> 1) * 64, wn = (wave & 1) * 64;
  f32x4 acc[4][4] = {};

  for (int k0 = 0; k0 < K; k0 += 32) {
    __syncthreads();
    #pragma unroll
    for (int i = 0; i < 2; ++i) {
      const int f = i * 256 + tid;
      const int r = f >> 2;
      const int c = (f & 3) ^ ((r >> 1) & 3);   // pre-swizzled source chunk
      gload16(A + (size_t)(m0 + r) * K + (k0 + c * 8), &sA[(i * 256 + wave * 64) * 8]);
      gload16(B + (size_t)(n0 + r) * K + (k0 + c * 8), &sB[(i * 256 + wave * 64) * 8]);
    }
    __syncthreads();
    short8 af[4], bf8[4];
    #pragma unroll
    for (int i = 0; i < 4; ++i) {
      const int ra = wm + i * 16 + (lane & 15);
      af[i]  = *reinterpret_cast<const short8*>(&sA[ra * 32 + (((lane >> 4) ^ ((ra >> 1) & 3)) * 8)]);
      const int rb = wn + i * 16 + (lane & 15);
      bf8[i] = *reinterpret_cast<const short8*>(&sB[rb * 32 + (((lane >> 4) ^ ((rb >> 1) & 3)) * 8)]);
    }
    #pragma unroll
    for (int i = 0; i < 4; ++i)
      #pragma unroll
      for (int j = 0; j < 4; ++j)
        acc[i][j] = mfma16(af[i], bf8[j], acc[i][j]);
  }

  #pragma unroll
  for (int i = 0; i < 4; ++i) {
    #pragma unroll
    for (int j = 0; j < 4; ++j) {
      #pragma unroll
      for (int r = 0; r < 4; ++r) {
        const int row = m0 + wm + i * 16 + ((lane >> 4) * 4) + r;
        const int col = n0 + wn + j * 16 + (lane & 15);
        const size_t idx = (size_t)row * N + col;
        float v = acc[i][j][r];
        if constexpr (EPI == 0) {
          outb[idx] = f2bf(v);
        } else if constexpr (EPI == 1) {
          outf[idx] = v + bias[col] + res[idx];
        } else {
          v += bias[col];
          v = 0.5f * v * (1.f + erff(v * 0.70710678118654752f));
          outb[idx] = f2bf(v);
        }
      }
    }
  }
}

// ---------------- flash attention (no 1/sqrt(d) scaling, per reference) ----------------
// grid: (B*H=64, SEQ/128=16). block 256 (4 waves). Each wave: 32 q-rows.
// qkv layout: [8192, 3072] bf16; q at col h*64, k at 1024+h*64, v at 2048+h*64.
__global__ __launch_bounds__(256) void attn_kernel(const ushort* __restrict__ qkv,
                                                   ushort* __restrict__ outp) {
  const int tid = threadIdx.x, lane = tid & 63, wave = tid >> 6;
  const int b = blockIdx.x >> 4, h = blockIdx.x & 15;
  const int q0 = blockIdx.y * 128;
  const size_t base = ((size_t)b * SEQ) * 3072 + h * 64;

  __shared__ ushort sK[64 * 64];        // swizzled rows of 128B
  __shared__ ushort sVt[64 * 72];       // V^T, stride 72 (aligned, conflict-free)
  __shared__ ushort sP[4][32 * 72];     // per-wave P; also reused as Q staging
  ushort* sQ = &sP[0][0];

  // stage Q [128][64] (swizzled) and pull fragments to registers
  #pragma unroll
  for (int i = 0; i < 4; ++i) {
    const int f = i * 256 + tid;
    const int r = f >> 3;
    const int c = (f & 7) ^ (r & 7);
    gload16(qkv + base + (size_t)(q0 + r) * 3072 + c * 8, &sQ[(i * 256 + wave * 64) * 8]);
  }
  __syncthreads();
  short8 qf[2][2];
  #pragma unroll
  for (int fm = 0; fm < 2; ++fm)
    #pragma unroll
    for (int fk = 0; fk < 2; ++fk) {
      const int r = wave * 32 + fm * 16 + (lane & 15);
      const int c = (fk * 4 + (lane >> 4)) ^ (r & 7);
      qf[fm][fk] = *reinterpret_cast<const short8*>(&sQ[r * 64 + c * 8]);
    }
  __syncthreads();

  f32x4 oacc[2][4] = {};
  float mst[2][4], lst[2][4];
  #pragma unroll
  for (int a = 0; a < 2; ++a)
    #pragma unroll
    for (int r = 0; r < 4; ++r) { mst[a][r] = -1e30f; lst[a][r] = 0.f; }

  for (int kt = 0; kt < SEQ; kt += 64) {
    __syncthreads();
    // stage K tile [64][64] via global_load_lds (swizzled)
    #pragma unroll
    for (int i = 0; i < 2; ++i) {
      const int f = i * 256 + tid;
      const int r = f >> 3;
      const int c = (f & 7) ^ (r & 7);
      gload16(qkv + base + 1024 + (size_t)(kt + r) * 3072 + c * 8, &sK[(i * 256 + wave * 64) * 8]);
    }
    // gather-transpose V tile into sVt[d][kv] (coalesced global reads)
    #pragma unroll
    for (int i = 0; i < 2; ++i) {
      const int ch = wave * 2 + i;
      short8 pk;
      #pragma unroll
      for (int r = 0; r < 8; ++r)
        pk[r] = (short)qkv[base + 2048 + (size_t)(kt + ch * 8 + r) * 3072 + lane];
      *reinterpret_cast<short8*>(&sVt[lane * 72 + ch * 8]) = pk;
    }
    __syncthreads();

    // S = Q K^T   [32 q x 64 kv] per wave
    f32x4 s[2][4];
    #pragma unroll
    for (int fn = 0; fn < 4; ++fn) {
      short8 kb[2];
      #pragma unroll
      for (int fk = 0; fk < 2; ++fk) {
        const int r = fn * 16 + (lane & 15);
        const int c = (fk * 4 + (lane >> 4)) ^ (r & 7);
        kb[fk] = *reinterpret_cast<const short8*>(&sK[r * 64 + c * 8]);
      }
      #pragma unroll
      for (int fm = 0; fm < 2; ++fm) {
        f32x4 t = {0.f, 0.f, 0.f, 0.f};
        t = mfma16(qf[fm][0], kb[0], t);
        t = mfma16(qf[fm][1], kb[1], t);
        s[fm][fn] = t;
      }
    }

    // online softmax (row = fm*16 + (lane>>4)*4 + r; 16-lane group reductions)
    #pragma unroll
    for (int fm = 0; fm < 2; ++fm) {
      #pragma unroll
      for (int r = 0; r < 4; ++r) {
        float mx = fmaxf(fmaxf(s[fm][0][r], s[fm][1][r]), fmaxf(s[fm][2][r], s[fm][3][r]));
        #pragma unroll
        for (int off = 1; off < 16; off <<= 1) mx = fmaxf(mx, __shfl_xor(mx, off));
        const float mo = mst[fm][r];
        const float mn = fmaxf(mo, mx);
        const float alpha = __expf(mo - mn);
        float rsum = 0.f;
        ushort pb[4];
        #pragma unroll
        for (int fn = 0; fn < 4; ++fn) {
          const float p = __expf(s[fm][fn][r] - mn);
          rsum += p;
          pb[fn] = f2bf(p);
        }
        #pragma unroll
        for (int off = 1; off < 16; off <<= 1) rsum += __shfl_xor(rsum, off);
        mst[fm][r] = mn;
        lst[fm][r] = lst[fm][r] * alpha + rsum;
        #pragma unroll
        for (int fd = 0; fd < 4; ++fd) oacc[fm][fd][r] *= alpha;
        const int prow = fm * 16 + (lane >> 4) * 4 + r;
        #pragma unroll
        for (int fn = 0; fn < 4; ++fn)
          sP[wave][prow * 72 + fn * 16 + (lane & 15)] = pb[fn];
      }
    }

    // O += P V   (P via per-wave LDS re-layout; V^T gives contiguous B frags)
    short8 pa[2][2];
    #pragma unroll
    for (int fm = 0; fm < 2; ++fm)
      #pragma unroll
      for (int fk = 0; fk < 2; ++fk)
        pa[fm][fk] = *reinterpret_cast<const short8*>(
            &sP[wave][(fm * 16 + (lane & 15)) * 72 + fk * 32 + (lane >> 4) * 8]);
    #pragma unroll
    for (int fd = 0; fd < 4; ++fd) {
      short8 vb[2];
      #pragma unroll
      for (int fk = 0; fk < 2; ++fk)
        vb[fk] = *reinterpret_cast<const short8*>(
            &sVt[(fd * 16 + (lane & 15)) * 72 + fk * 32 + (lane >> 4) * 8]);
      #pragma unroll
      for (int fm = 0; fm < 2; ++fm) {
        oacc[fm][fd] = mfma16(pa[fm][0], vb[0], oacc[fm][fd]);
        oacc[fm][fd] = mfma16(pa[fm][1], vb[1], oacc[fm][fd]);
      }
    }
  }

  // write O (head-concat layout [8192, 1024])
  #pragma unroll
  for (int fm = 0; fm < 2; ++fm)
    #pragma unroll
    for (int fd = 0; fd < 4; ++fd)
      #pragma unroll
      for (int r = 0; r < 4; ++r) {
        const int row = q0 + wave * 32 + fm * 16 + (lane >> 4) * 4 + r;
        const int col = h * 64 + fd * 16 + (lane & 15);
        outp[((size_t)b * SEQ + row) * EMBED + col] = f2bf(oacc[fm][fd][r] / lst[fm][r]);
      }
}

// ---------------- launch ----------------
extern "C" void kernel_launch(void* const* d_in, const int* in_sizes, int n_in,
                              void* d_out, int out_size, void* d_ws, size_t ws_size,
                              hipStream_t stream) {
  const float* x     = (const float*)d_in[0];
  const float* ln1_g = (const float*)d_in[1];
  const float* ln1_b = (const float*)d_in[2];
  const float* qkv_w = (const float*)d_in[3];
  const float* out_w = (const float*)d_in[4];
  const float* out_b = (const float*)d_in[5];
  const float* ln2_g = (const float*)d_in[6];
  const float* ln2_b = (const float*)d_in[7];
  const float* fc1_w = (const float*)d_in[8];
  const float* fc1_b = (const float*)d_in[9];
  const float* fc2_w = (const float*)d_in[10];
  const float* fc2_b = (const float*)d_in[11];
  float* out = (float*)d_out;
  char* ws = (char*)d_ws;

  // workspace layout (bytes)
  ushort* qkvw = (ushort*)(ws);                                   //  6291456
  ushort* outw = (ushort*)(ws + 6291456);                         //  2097152
  ushort* fc1w = (ushort*)(ws + 8388608);                         //  8388608
  ushort* fc2w = (ushort*)(ws + 16777216);                        //  8388608
  float*  x1   = (float*) (ws + 25165824);                        // 33554432
  ushort* hbuf = (ushort*)(ws + 58720256);                        // 16777216
  ushort* qkvb = (ushort*)(ws + 75497472);                        // 50331648
  ushort* obuf = (ushort*)(ws + 125829120);                       // 16777216
  ushort* gbuf = qkvb;  // gelu buf [8192,4096] bf16 reuses qkv+o regions (exactly 64 MiB)

  cvt_bf16_kernel<<<3072, 256, 0, stream>>>(qkv_w, qkvw, 3 * EMBED * EMBED / 4);
  cvt_bf16_kernel<<<1024, 256, 0, stream>>>(out_w, outw, EMBED * EMBED / 4);
  cvt_bf16_kernel<<<4096, 256, 0, stream>>>(fc1_w, fc1w, HIDDEN * EMBED / 4);
  cvt_bf16_kernel<<<4096, 256, 0, stream>>>(fc2_w, fc2w, EMBED * HIDDEN / 4);

  ln_kernel<<<NTOK, 256, 0, stream>>>(x, ln1_g, ln1_b, hbuf);
  gemm_bt<0><<<dim3(64, 24), 256, 0, stream>>>(hbuf, qkvw, nullptr, nullptr,
                                               qkvb, nullptr, NTOK, 3 * EMBED, EMBED);
  attn_kernel<<<dim3(64, 16), 256, 0, stream>>>(qkvb, obuf);
  gemm_bt<1><<<dim3(64, 8), 256, 0, stream>>>(obuf, outw, out_b, x,
                                              nullptr, x1, NTOK, EMBED, EMBED);
  ln_kernel<<<NTOK, 256, 0, stream>>>(x1, ln2_g, ln2_b, hbuf);
  gemm_bt<2><<<dim3(64, 32), 256, 0, stream>>>(hbuf, fc1w, fc1_b, nullptr,
                                               gbuf, nullptr, NTOK, HIDDEN, EMBED);
  gemm_bt<1><<<dim3(64, 8), 256, 0, stream>>>(gbuf, fc2w, fc2_b, x1,
                                              nullptr, out, NTOK, EMBED, HIDDEN);
}

// Round 2
// 467.619 us; speedup vs baseline: 1.3269x; 1.3269x over previous
//
#include <hip/hip_runtime.h>
#include <cstdint>

// Transformer block: LN1 -> {QK GEMM, V^T GEMM} -> flash attn (swapped-QK,
// in-register softmax, permlane P re-layout) -> out-proj(+res) -> LN2
// -> fc1(+GELU) -> fc2(+res). All matmuls bf16 MFMA, fp32 accum.

using short8 = __attribute__((ext_vector_type(8))) short;
using f32x4  = __attribute__((ext_vector_type(4))) float;
using f32x16 = __attribute__((ext_vector_type(16))) float;

#define EMBED  1024
#define HIDDEN 4096
#define SEQ    2048
#define NTOK   8192   // 4*2048

__device__ __forceinline__ ushort f2bf(float x) {
  union { float f; uint32_t u; } v; v.f = x;
  uint32_t r = v.u + 0x7fffu + ((v.u >> 16) & 1u);   // RNE
  return (ushort)(r >> 16);
}

__device__ __forceinline__ uint32_t pkbf(float lo, float hi) {
  uint32_t r;
  asm("v_cvt_pk_bf16_f32 %0, %1, %2" : "=v"(r) : "v"(lo), "v"(hi));
  return r;
}

__device__ __forceinline__ void gload16(const void* g, void* l) {
  __builtin_amdgcn_global_load_lds((__attribute__((address_space(1))) void*)(g),
                                   (__attribute__((address_space(3))) void*)(l), 16, 0, 0);
}

__device__ __forceinline__ f32x4 mfma16(short8 a, short8 b, f32x4 c) {
  return __builtin_amdgcn_mfma_f32_16x16x32_bf16(a, b, c, 0, 0, 0);
}
__device__ __forceinline__ f32x16 mfma32(short8 a, short8 b, f32x16 c) {
  return __builtin_amdgcn_mfma_f32_32x32x16_bf16(a, b, c, 0, 0, 0);
}
__device__ __forceinline__ f32x16 zero16() {
  f32x16 z = {0.f,0.f,0.f,0.f,0.f,0.f,0.f,0.f,0.f,0.f,0.f,0.f,0.f,0.f,0.f,0.f};
  return z;
}

// ---------------- fp32 -> bf16 weight conversion ----------------
__global__ __launch_bounds__(256) void cvt_bf16_kernel(const float* __restrict__ in,
                                                       ushort* __restrict__ out, int n4) {
  int i = blockIdx.x * 256 + threadIdx.x;
  if (i < n4) {
    float4 v = reinterpret_cast<const float4*>(in)[i];
    ushort4 o; o.x = f2bf(v.x); o.y = f2bf(v.y); o.z = f2bf(v.z); o.w = f2bf(v.w);
    reinterpret_cast<ushort4*>(out)[i] = o;
  }
}

// ---------------- LayerNorm (fp32 in, bf16 out) ----------------
__global__ __launch_bounds__(256) void ln_kernel(const float* __restrict__ x,
                                                 const float* __restrict__ g,
                                                 const float* __restrict__ b,
                                                 ushort* __restrict__ out) {
  const int row = blockIdx.x, tid = threadIdx.x;
  const float4 xv = reinterpret_cast<const float4*>(x + (size_t)row * EMBED)[tid];
  float s  = xv.x + xv.y + xv.z + xv.w;
  float s2 = xv.x*xv.x + xv.y*xv.y + xv.z*xv.z + xv.w*xv.w;
  #pragma unroll
  for (int off = 32; off >= 1; off >>= 1) { s += __shfl_xor(s, off); s2 += __shfl_xor(s2, off); }
  __shared__ float ps[4], ps2[4];
  if ((tid & 63) == 0) { ps[tid >> 6] = s; ps2[tid >> 6] = s2; }
  __syncthreads();
  s  = ps[0] + ps[1] + ps[2] + ps[3];
  s2 = ps2[0] + ps2[1] + ps2[2] + ps2[3];
  const float mu  = s * (1.f / EMBED);
  const float var = s2 * (1.f / EMBED) - mu * mu;
  const float rs  = rsqrtf(var + 1e-5f);
  const float4 gv = reinterpret_cast<const float4*>(g)[tid];
  const float4 bv = reinterpret_cast<const float4*>(b)[tid];
  ushort4 o;
  o.x = f2bf((xv.x - mu) * rs * gv.x + bv.x);
  o.y = f2bf((xv.y - mu) * rs * gv.y + bv.y);
  o.z = f2bf((xv.z - mu) * rs * gv.z + bv.z);
  o.w = f2bf((xv.w - mu) * rs * gv.w + bv.w);
  reinterpret_cast<ushort4*>(out + (size_t)row * EMBED)[tid] = o;
}

// ---------------- bf16 GEMM: C[M,N] = A[M,K] * B[N,K]^T (+epilogue) ----------------
template<int EPI>
__global__ __launch_bounds__(256) void gemm_bt(const ushort* __restrict__ A,
                                               const ushort* __restrict__ B,
                                               const float* __restrict__ bias,
                                               const float* __restrict__ res,
                                               ushort* __restrict__ outb,
                                               float* __restrict__ outf,
                                               int M, int N, int K) {
  __shared__ ushort sA[128 * 32];
  __shared__ ushort sB[128 * 32];
  const int tid = threadIdx.x, lane = tid & 63, wave = tid >> 6;
  const int m0 = blockIdx.x * 128, n0 = blockIdx.y * 128;
  const int wm = (wave >> 1) * 64, wn = (wave & 1) * 64;
  f32x4 acc[4][4] = {};

  for (int k0 = 0; k0 < K; k0 += 32) {
    __syncthreads();
    #pragma unroll
    for (int i = 0; i < 2; ++i) {
      const int f = i * 256 + tid;
      const int r = f >> 2;
      const int c = (f & 3) ^ ((r >> 1) & 3);
      gload16(A + (size_t)(m0 + r) * K + (k0 + c * 8), &sA[(i * 256 + wave * 64) * 8]);
      gload16(B + (size_t)(n0 + r) * K + (k0 + c * 8), &sB[(i * 256 + wave * 64) * 8]);
    }
    __syncthreads();
    short8 af[4], bf8[4];
    #pragma unroll
    for (int i = 0; i < 4; ++i) {
      const int ra = wm + i * 16 + (lane & 15);
      af[i]  = *reinterpret_cast<const short8*>(&sA[ra * 32 + (((lane >> 4) ^ ((ra >> 1) & 3)) * 8)]);
      const int rb = wn + i * 16 + (lane & 15);
      bf8[i] = *reinterpret_cast<const short8*>(&sB[rb * 32 + (((lane >> 4) ^ ((rb >> 1) & 3)) * 8)]);
    }
    #pragma unroll
    for (int i = 0; i < 4; ++i)
      #pragma unroll
      for (int j = 0; j < 4; ++j)
        acc[i][j] = mfma16(af[i], bf8[j], acc[i][j]);
  }

  #pragma unroll
  for (int i = 0; i < 4; ++i) {
    #pragma unroll
    for (int j = 0; j < 4; ++j) {
      #pragma unroll
      for (int r = 0; r < 4; ++r) {
        const int row = m0 + wm + i * 16 + ((lane >> 4) * 4) + r;
        const int col = n0 + wn + j * 16 + (lane & 15);
        const size_t idx = (size_t)row * N + col;
        float v = acc[i][j][r];
        if constexpr (EPI == 0) {
          outb[idx] = f2bf(v);
        } else if constexpr (EPI == 1) {
          outf[idx] = v + bias[col] + res[idx];
        } else {
          v += bias[col];
          v = 0.5f * v * (1.f + erff(v * 0.70710678118654752f));
          outb[idx] = f2bf(v);
        }
      }
    }
  }
}

// ---------------- flash attention, swapped-QK in-register softmax ----------------
// grid (B*H=64, SEQ/256=8), block 256 (4 waves). Wave: 64 q rows (2 sets of 32).
// qk: [8192][2048] bf16 (q at col h*64, k at col 1024+h*64). vt: [1024][8192] bf16.
// No 1/sqrt(d) scaling (per reference).
#define KVB 64
#define NT  (SEQ / KVB)

__global__ __launch_bounds__(256, 2) void attn_kernel(const ushort* __restrict__ qk,
                                                      const ushort* __restrict__ vt,
                                                      ushort* __restrict__ outp) {
  const int tid = threadIdx.x, lane = tid & 63, wq = tid >> 6;
  const int hi = lane >> 5, lo = lane & 31;
  const int b = blockIdx.x >> 4, h = blockIdx.x & 15;
  const int q0 = blockIdx.y * 256;

  __shared__ ushort sK[2][64 * 64];
  __shared__ ushort sVt[2][64 * 64];
  __shared__ float sBc[4][2][32];

  // Q fragments (B-operand): row q, k-chunk (hi*8) within kc*16
  short8 qf[2][4];
  #pragma unroll
  for (int s = 0; s < 2; ++s)
    #pragma unroll
    for (int kc = 0; kc < 4; ++kc)
      qf[s][kc] = *reinterpret_cast<const short8*>(
          qk + (size_t)(b * SEQ + q0 + wq * 64 + s * 32 + lo) * 2048 + h * 64 + kc * 16 + hi * 8);

  auto STAGE = [&](int bb, int kt) {
    #pragma unroll
    for (int i = 0; i < 2; ++i) {
      const int slot = i * 256 + tid;
      const int r = slot >> 3;
      const int c = (slot & 7) ^ (r & 7);           // inverse-swizzled source chunk
      gload16(qk + (size_t)(b * SEQ + kt + r) * 2048 + 1024 + h * 64 + c * 8,
              &sK[bb][(i * 256 + wq * 64) * 8]);
      gload16(vt + (size_t)(h * 64 + r) * 8192 + b * SEQ + kt + c * 8,
              &sVt[bb][(i * 256 + wq * 64) * 8]);
    }
  };

  f32x16 acc[2][2];
  #pragma unroll
  for (int s = 0; s < 2; ++s) { acc[s][0] = zero16(); acc[s][1] = zero16(); }
  float mst[2] = {-1e30f, -1e30f}, lst[2] = {0.f, 0.f};

  STAGE(0, 0);
  for (int t = 0; t < NT; ++t) {
    const int cur = t & 1;
    __syncthreads();                       // staged buf[cur] ready; buf[cur^1] free
    if (t + 1 < NT) STAGE(cur ^ 1, (t + 1) * KVB);

    // K fragments (A-operand): row kv, swizzled b128 reads
    short8 kf[2][4];
    #pragma unroll
    for (int kvb = 0; kvb < 2; ++kvb)
      #pragma unroll
      for (int kc = 0; kc < 4; ++kc) {
        const int row = kvb * 32 + lo, ch = kc * 2 + hi;
        kf[kvb][kc] = *reinterpret_cast<const short8*>(
            &sK[cur][(row * 8 + (ch ^ (row & 7))) * 8]);
      }

    short8 pa[2][4];
    #pragma unroll
    for (int s = 0; s < 2; ++s) {
      // S^T = K * Q^T : lane holds q=lo, kv rows in regs
      f32x16 st[2];
      #pragma unroll
      for (int kvb = 0; kvb < 2; ++kvb) {
        f32x16 tq = zero16();
        tq = mfma32(kf[kvb][0], qf[s][0], tq);
        tq = mfma32(kf[kvb][1], qf[s][1], tq);
        tq = mfma32(kf[kvb][2], qf[s][2], tq);
        tq = mfma32(kf[kvb][3], qf[s][3], tq);
        st[kvb] = tq;
      }
      // row max: in-register tree + one cross-half swap
      float pm = fmaxf(st[0][0], st[0][1]);
      #pragma unroll
      for (int r = 2; r < 16; ++r) pm = fmaxf(pm, st[0][r]);
      #pragma unroll
      for (int r = 0; r < 16; ++r) pm = fmaxf(pm, st[1][r]);
      pm = fmaxf(pm, __shfl_xor(pm, 32));
      // defer-max: rescale only when max grew by > 8
      if (__any(pm > mst[s] + 8.f)) {
        const float mn = fmaxf(mst[s], pm);
        const float al = __expf(mst[s] - mn);
        mst[s] = mn; lst[s] *= al;
        sBc[wq][s][lo] = al;
        asm volatile("s_waitcnt lgkmcnt(0)" ::: "memory");
        #pragma unroll
        for (int g = 0; g < 4; ++g) {
          const f32x4 a4 = *reinterpret_cast<const f32x4*>(&sBc[wq][s][g * 8 + hi * 4]);
          #pragma unroll
          for (int j = 0; j < 4; ++j) {
            acc[s][0][g * 4 + j] *= a4[j];
            acc[s][1][g * 4 + j] *= a4[j];
          }
        }
      }
      // P = exp(S - m), row sum
      #pragma unroll
      for (int kvb = 0; kvb < 2; ++kvb)
        #pragma unroll
        for (int r = 0; r < 16; ++r)
          st[kvb][r] = __expf(st[kvb][r] - mst[s]);
      {
        const f32x16 sv = st[0] + st[1];
        float sum = ((sv[0] + sv[1]) + (sv[2] + sv[3])) + ((sv[4] + sv[5]) + (sv[6] + sv[7]))
                  + ((sv[8] + sv[9]) + (sv[10] + sv[11])) + ((sv[12] + sv[13]) + (sv[14] + sv[15]));
        sum += __shfl_xor(sum, 32);
        lst[s] += sum;
      }
      // pack P -> bf16 A-fragments via cvt_pk + permlane32_swap
      #pragma unroll
      for (int kvb = 0; kvb < 2; ++kvb)
        #pragma unroll
        for (int f = 0; f < 2; ++f) {
          uint32_t wa = pkbf(st[kvb][f * 8 + 0], st[kvb][f * 8 + 1]);
          uint32_t wb = pkbf(st[kvb][f * 8 + 2], st[kvb][f * 8 + 3]);
          uint32_t wc = pkbf(st[kvb][f * 8 + 4], st[kvb][f * 8 + 5]);
          uint32_t wd = pkbf(st[kvb][f * 8 + 6], st[kvb][f * 8 + 7]);
          asm volatile("v_permlane32_swap_b32 %0, %1" : "+v"(wa), "+v"(wc));
          asm volatile("v_permlane32_swap_b32 %0, %1" : "+v"(wb), "+v"(wd));
          union { uint32_t w[4]; short8 v; } u;
          u.w[0] = wa; u.w[1] = wb; u.w[2] = wc; u.w[3] = wd;
          pa[s][kvb * 2 + f] = u.v;
        }
    }

    // O += P V  (B-operand = V^T rows d)
    #pragma unroll
    for (int db = 0; db < 2; ++db) {
      short8 vb[4];
      #pragma unroll
      for (int k4 = 0; k4 < 4; ++k4) {
        const int row = db * 32 + lo, ch = k4 * 2 + hi;
        vb[k4] = *reinterpret_cast<const short8*>(
            &sVt[cur][(row * 8 + (ch ^ (row & 7))) * 8]);
      }
      #pragma unroll
      for (int s = 0; s < 2; ++s) {
        acc[s][db] = mfma32(pa[s][0], vb[0], acc[s][db]);
        acc[s][db] = mfma32(pa[s][1], vb[1], acc[s][db]);
        acc[s][db] = mfma32(pa[s][2], vb[2], acc[s][db]);
        acc[s][db] = mfma32(pa[s][3], vb[3], acc[s][db]);
      }
    }
  }

  // epilogue: O /= l, write bf16 [8192][1024]
  #pragma unroll
  for (int s = 0; s < 2; ++s) sBc[wq][s][lo] = 1.f / lst[s];
  asm volatile("s_waitcnt lgkmcnt(0)" ::: "memory");
  #pragma unroll
  for (int s = 0; s < 2; ++s)
    #pragma unroll
    for (int g = 0; g < 4; ++g) {
      const f32x4 r4 = *reinterpret_cast<const f32x4*>(&sBc[wq][s][g * 8 + hi * 4]);
      #pragma unroll
      for (int j = 0; j < 4; ++j) {
        const int qrow = q0 + wq * 64 + s * 32 + g * 8 + hi * 4 + j;
        #pragma unroll
        for (int db = 0; db < 2; ++db)
          outp[(size_t)(b * SEQ + qrow) * EMBED + h * 64 + db * 32 + lo] =
              f2bf(acc[s][db][g * 4 + j] * r4[j]);
      }
    }
}

// ---------------- launch ----------------
extern "C" void kernel_launch(void* const* d_in, const int* in_sizes, int n_in,
                              void* d_out, int out_size, void* d_ws, size_t ws_size,
                              hipStream_t stream) {
  const float* x     = (const float*)d_in[0];
  const float* ln1_g = (const float*)d_in[1];
  const float* ln1_b = (const float*)d_in[2];
  const float* qkv_w = (const float*)d_in[3];
  const float* out_w = (const float*)d_in[4];
  const float* out_b = (const float*)d_in[5];
  const float* ln2_g = (const float*)d_in[6];
  const float* ln2_b = (const float*)d_in[7];
  const float* fc1_w = (const float*)d_in[8];
  const float* fc1_b = (const float*)d_in[9];
  const float* fc2_w = (const float*)d_in[10];
  const float* fc2_b = (const float*)d_in[11];
  float* out = (float*)d_out;
  char* ws = (char*)d_ws;

  // workspace layout (bytes)
  ushort* qkvw = (ushort*)(ws);                                   //  6291456
  ushort* outw = (ushort*)(ws + 6291456);                         //  2097152
  ushort* fc1w = (ushort*)(ws + 8388608);                         //  8388608
  ushort* fc2w = (ushort*)(ws + 16777216);                        //  8388608
  float*  x1   = (float*) (ws + 25165824);                        // 33554432
  ushort* hbuf = (ushort*)(ws + 58720256);                        // 16777216
  ushort* qkbuf= (ushort*)(ws + 75497472);                        // 33554432  [8192][2048]
  ushort* vtbuf= (ushort*)(ws + 109051904);                       // 16777216  [1024][8192]
  ushort* obuf = (ushort*)(ws + 125829120);                       // 16777216
  ushort* gbuf = qkbuf;  // gelu buf [8192][4096] reuses qk+vt+o regions (64 MiB)

  cvt_bf16_kernel<<<3072, 256, 0, stream>>>(qkv_w, qkvw, 3 * EMBED * EMBED / 4);
  cvt_bf16_kernel<<<1024, 256, 0, stream>>>(out_w, outw, EMBED * EMBED / 4);
  cvt_bf16_kernel<<<4096, 256, 0, stream>>>(fc1_w, fc1w, HIDDEN * EMBED / 4);
  cvt_bf16_kernel<<<4096, 256, 0, stream>>>(fc2_w, fc2w, EMBED * HIDDEN / 4);

  ln_kernel<<<NTOK, 256, 0, stream>>>(x, ln1_g, ln1_b, hbuf);
  // QK: [8192][2048] = hbuf * Wqk^T
  gemm_bt<0><<<dim3(64, 16), 256, 0, stream>>>(hbuf, qkvw, nullptr, nullptr,
                                               qkbuf, nullptr, NTOK, 2 * EMBED, EMBED);
  // V^T: [1024][8192] = Wv * hbuf^T
  gemm_bt<0><<<dim3(8, 64), 256, 0, stream>>>(qkvw + 2048 * 1024, hbuf, nullptr, nullptr,
                                              vtbuf, nullptr, EMBED, NTOK, EMBED);
  attn_kernel<<<dim3(64, 8), 256, 0, stream>>>(qkbuf, vtbuf, obuf);
  gemm_bt<1><<<dim3(64, 8), 256, 0, stream>>>(obuf, outw, out_b, x,
                                              nullptr, x1, NTOK, EMBED, EMBED);
  ln_kernel<<<NTOK, 256, 0, stream>>>(x1, ln2_g, ln2_b, hbuf);
  gemm_bt<2><<<dim3(64, 32), 256, 0, stream>>>(hbuf, fc1w, fc1_b, nullptr,
                                               gbuf, nullptr, NTOK, HIDDEN, EMBED);
  gemm_bt<1><<<dim3(64, 8), 256, 0, stream>>>(gbuf, fc2w, fc2_b, x1,
                                              nullptr, out, NTOK, EMBED, HIDDEN);
}

// Round 3
// 424.845 us; speedup vs baseline: 1.4605x; 1.1007x over previous
//
#include <hip/hip_runtime.h>
#include <cstdint>

// Transformer block: LN1 -> {QK GEMM, V^T GEMM} -> flash attn (swapped-QK,
// in-register softmax, permlane P re-layout) -> out-proj(+res) -> LN2
// -> fc1(+GELU) -> fc2(+res). All matmuls bf16 MFMA, fp32 accum.
// GEMM: 256-wide tiles, quad-buffered LDS, counted-vmcnt deep pipeline,
// raw s_barrier + setprio (T2+T3+T4+T5 per the CDNA4 guide).

using short8 = __attribute__((ext_vector_type(8))) short;
using f32x4  = __attribute__((ext_vector_type(4))) float;
using f32x16 = __attribute__((ext_vector_type(16))) float;

#define EMBED  1024
#define HIDDEN 4096
#define SEQ    2048
#define NTOK   8192   // 4*2048

__device__ __forceinline__ ushort f2bf(float x) {
  union { float f; uint32_t u; } v; v.f = x;
  uint32_t r = v.u + 0x7fffu + ((v.u >> 16) & 1u);   // RNE
  return (ushort)(r >> 16);
}

__device__ __forceinline__ uint32_t pkbf(float lo, float hi) {
  uint32_t r;
  asm("v_cvt_pk_bf16_f32 %0, %1, %2" : "=v"(r) : "v"(lo), "v"(hi));
  return r;
}

__device__ __forceinline__ void gload16(const void* g, void* l) {
  __builtin_amdgcn_global_load_lds((__attribute__((address_space(1))) void*)(g),
                                   (__attribute__((address_space(3))) void*)(l), 16, 0, 0);
}

template<int N> __device__ __forceinline__ void vwait() {
  asm volatile("s_waitcnt vmcnt(%0)" :: "n"(N) : "memory");
}
__device__ __forceinline__ void fence_bar() {
  asm volatile("" ::: "memory");
  __builtin_amdgcn_s_barrier();
  asm volatile("" ::: "memory");
}

__device__ __forceinline__ f32x4 mfma16(short8 a, short8 b, f32x4 c) {
  return __builtin_amdgcn_mfma_f32_16x16x32_bf16(a, b, c, 0, 0, 0);
}
__device__ __forceinline__ f32x16 mfma32(short8 a, short8 b, f32x16 c) {
  return __builtin_amdgcn_mfma_f32_32x32x16_bf16(a, b, c, 0, 0, 0);
}
__device__ __forceinline__ f32x16 zero16() {
  f32x16 z = {0.f,0.f,0.f,0.f,0.f,0.f,0.f,0.f,0.f,0.f,0.f,0.f,0.f,0.f,0.f,0.f};
  return z;
}

// ---------------- fp32 -> bf16 weight conversion ----------------
__global__ __launch_bounds__(256) void cvt_bf16_kernel(const float* __restrict__ in,
                                                       ushort* __restrict__ out, int n4) {
  int i = blockIdx.x * 256 + threadIdx.x;
  if (i < n4) {
    float4 v = reinterpret_cast<const float4*>(in)[i];
    ushort4 o; o.x = f2bf(v.x); o.y = f2bf(v.y); o.z = f2bf(v.z); o.w = f2bf(v.w);
    reinterpret_cast<ushort4*>(out)[i] = o;
  }
}

// ---------------- LayerNorm (fp32 in, bf16 out) ----------------
__global__ __launch_bounds__(256) void ln_kernel(const float* __restrict__ x,
                                                 const float* __restrict__ g,
                                                 const float* __restrict__ b,
                                                 ushort* __restrict__ out) {
  const int row = blockIdx.x, tid = threadIdx.x;
  const float4 xv = reinterpret_cast<const float4*>(x + (size_t)row * EMBED)[tid];
  float s  = xv.x + xv.y + xv.z + xv.w;
  float s2 = xv.x*xv.x + xv.y*xv.y + xv.z*xv.z + xv.w*xv.w;
  #pragma unroll
  for (int off = 32; off >= 1; off >>= 1) { s += __shfl_xor(s, off); s2 += __shfl_xor(s2, off); }
  __shared__ float ps[4], ps2[4];
  if ((tid & 63) == 0) { ps[tid >> 6] = s; ps2[tid >> 6] = s2; }
  __syncthreads();
  s  = ps[0] + ps[1] + ps[2] + ps[3];
  s2 = ps2[0] + ps2[1] + ps2[2] + ps2[3];
  const float mu  = s * (1.f / EMBED);
  const float var = s2 * (1.f / EMBED) - mu * mu;
  const float rs  = rsqrtf(var + 1e-5f);
  const float4 gv = reinterpret_cast<const float4*>(g)[tid];
  const float4 bv = reinterpret_cast<const float4*>(b)[tid];
  ushort4 o;
  o.x = f2bf((xv.x - mu) * rs * gv.x + bv.x);
  o.y = f2bf((xv.y - mu) * rs * gv.y + bv.y);
  o.z = f2bf((xv.z - mu) * rs * gv.z + bv.z);
  o.w = f2bf((xv.w - mu) * rs * gv.w + bv.w);
  reinterpret_cast<ushort4*>(out + (size_t)row * EMBED)[tid] = o;
}

// ---------------- bf16 GEMM: C[M,N] = A[M,K] * B[N,K]^T (+epilogue) ----------------
// SQ=true: 256x256 tile (8 waves 2Mx4N, wave out 128x64).
// SQ=false: 256x128 tile (8 waves 4Mx2N, wave out 64x64).
// Quad-buffered BK=32 tiles; stage tile u+3 during tile u; counted vmcnt.
// EPI 0: outb = bf16(acc); 1: outf = acc + bias + res; 2: outb = bf16(gelu(acc+bias))
template<int EPI, bool SQ>
__global__ __launch_bounds__(512) void gemm256(const ushort* __restrict__ A,
                                               const ushort* __restrict__ B,
                                               const float* __restrict__ bias,
                                               const float* __restrict__ res,
                                               ushort* __restrict__ outb,
                                               float* __restrict__ outf,
                                               int M, int N, int K, int gx) {
  constexpr int BN   = SQ ? 256 : 128;
  constexpr int MP   = SQ ? 8 : 4;          // 16-row m-positions per wave
  constexpr int NPH  = SQ ? 2 : 1;          // phases per K-tile
  constexpr int LPT  = SQ ? 4 : 3;          // gload16 rounds per tile per thread
  constexpr int ABUF = 256 * 32;            // ushorts
  constexpr int BBUF = BN * 32;
  __shared__ ushort lds[4][ABUF + BBUF];

  const int nwg = gridDim.x;                // nwg % 8 == 0 for all our shapes
  const int b0  = blockIdx.x;
  const int bid = (b0 & 7) * (nwg >> 3) + (b0 >> 3);   // XCD-chunked swizzle
  const int m0  = (bid % gx) * 256;
  const int n0  = (bid / gx) * BN;

  const int tid = threadIdx.x, lane = tid & 63, wave = tid >> 6;
  const int wm = (SQ ? (wave >> 2) : (wave >> 1)) * (MP * 16);
  const int wn = (SQ ? (wave & 3) : (wave & 1)) * 64;
  const int l15 = lane & 15, l4 = lane >> 4;
  const int NT = K >> 5;

  auto stageRound = [&](int buf, int kt, int round) {
    if (round < 2) {              // A rounds
      const int slot = round * 512 + tid;
      const int r = slot >> 2;
      const int cs = (slot & 3) ^ ((r >> 1) & 3);
      gload16(A + (size_t)(m0 + r) * K + kt + cs * 8, &lds[buf][slot * 8]);
    } else {                      // B rounds
      const int slot = (round - 2) * 512 + tid;
      const int r = slot >> 2;
      const int cs = (slot & 3) ^ ((r >> 1) & 3);
      gload16(B + (size_t)(n0 + r) * K + kt + cs * 8, &lds[buf][ABUF + slot * 8]);
    }
  };

  // prologue: stage tiles 0..2 into bufs 0..2 (NT >= 32 always here)
  #pragma unroll
  for (int t = 0; t < 3; ++t)
    #pragma unroll
    for (int rd = 0; rd < LPT; ++rd)
      stageRound(t, t * 32, rd);
  vwait<2 * LPT>();               // tile 0 resident; 2 tiles stay in flight
  fence_bar();

  f32x4 acc[MP][4] = {};

  for (int u = 0; u < NT; ++u) {
    const ushort* bA = &lds[u & 3][0];
    const ushort* bB = &lds[u & 3][ABUF];
    const int sbuf = (u + 3) & 3;
    const int skt  = (u + 3) * 32;
    const bool st  = (u + 3 < NT);

    short8 bf[4];
    #pragma unroll
    for (int j = 0; j < 4; ++j) {
      const int rb = wn + j * 16 + l15;
      bf[j] = *reinterpret_cast<const short8*>(&bB[rb * 32 + ((l4 ^ ((rb >> 1) & 3)) * 8)]);
    }
    #pragma unroll
    for (int ph = 0; ph < NPH; ++ph) {
      short8 af[4];
      #pragma unroll
      for (int i = 0; i < 4; ++i) {
        const int ra = wm + (ph * 4 + i) * 16 + l15;
        af[i] = *reinterpret_cast<const short8*>(&bA[ra * 32 + ((l4 ^ ((ra >> 1) & 3)) * 8)]);
      }
      if (st) {
        if constexpr (SQ) {
          stageRound(sbuf, skt, ph * 2);
          stageRound(sbuf, skt, ph * 2 + 1);
        } else {
          stageRound(sbuf, skt, 0);
          stageRound(sbuf, skt, 1);
          stageRound(sbuf, skt, 2);
        }
      }
      fence_bar();
      __builtin_amdgcn_s_setprio(1);
      #pragma unroll
      for (int i = 0; i < 4; ++i)
        #pragma unroll
        for (int j = 0; j < 4; ++j)
          acc[ph * 4 + i][j] = mfma16(af[i], bf[j], acc[ph * 4 + i][j]);
      __builtin_amdgcn_s_setprio(0);
      if (ph == NPH - 1) {        // tile boundary: next tile must be resident
        if (u < NT - 3)       vwait<2 * LPT>();
        else if (u == NT - 3) vwait<LPT>();
        else if (u == NT - 2) vwait<0>();
      }
      fence_bar();
    }
  }

  #pragma unroll
  for (int i = 0; i < MP; ++i)
    #pragma unroll
    for (int j = 0; j < 4; ++j)
      #pragma unroll
      for (int r = 0; r < 4; ++r) {
        const int row = m0 + wm + i * 16 + l4 * 4 + r;
        const int col = n0 + wn + j * 16 + l15;
        const size_t idx = (size_t)row * N + col;
        float v = acc[i][j][r];
        if constexpr (EPI == 0) {
          outb[idx] = f2bf(v);
        } else if constexpr (EPI == 1) {
          outf[idx] = v + bias[col] + res[idx];
        } else {
          v += bias[col];
          v = 0.5f * v * (1.f + erff(v * 0.70710678118654752f));
          outb[idx] = f2bf(v);
        }
      }
}

// ---------------- flash attention, swapped-QK in-register softmax ----------------
// grid (B*H=64, SEQ/256=8), block 256 (4 waves). Wave: 64 q rows (2 sets of 32).
// qk: [8192][2048] bf16 (q at col h*64, k at col 1024+h*64). vt: [1024][8192] bf16.
// No 1/sqrt(d) scaling (per reference).
#define KVB 64
#define NTT (SEQ / KVB)

__global__ __launch_bounds__(256, 2) void attn_kernel(const ushort* __restrict__ qk,
                                                      const ushort* __restrict__ vt,
                                                      ushort* __restrict__ outp) {
  const int tid = threadIdx.x, lane = tid & 63, wq = tid >> 6;
  const int hi = lane >> 5, lo = lane & 31;
  const int b = blockIdx.x >> 4, h = blockIdx.x & 15;
  const int q0 = blockIdx.y * 256;

  __shared__ ushort sK[2][64 * 64];
  __shared__ ushort sVt[2][64 * 64];
  __shared__ float sBc[4][2][32];

  // Q fragments (B-operand): row q, k-chunk (hi*8) within kc*16
  short8 qf[2][4];
  #pragma unroll
  for (int s = 0; s < 2; ++s)
    #pragma unroll
    for (int kc = 0; kc < 4; ++kc)
      qf[s][kc] = *reinterpret_cast<const short8*>(
          qk + (size_t)(b * SEQ + q0 + wq * 64 + s * 32 + lo) * 2048 + h * 64 + kc * 16 + hi * 8);

  auto STAGE = [&](int bb, int kt) {
    #pragma unroll
    for (int i = 0; i < 2; ++i) {
      const int slot = i * 256 + tid;
      const int r = slot >> 3;
      const int c = (slot & 7) ^ (r & 7);           // inverse-swizzled source chunk
      gload16(qk + (size_t)(b * SEQ + kt + r) * 2048 + 1024 + h * 64 + c * 8,
              &sK[bb][(i * 256 + wq * 64) * 8]);
      gload16(vt + (size_t)(h * 64 + r) * 8192 + b * SEQ + kt + c * 8,
              &sVt[bb][(i * 256 + wq * 64) * 8]);
    }
  };

  f32x16 acc[2][2];
  #pragma unroll
  for (int s = 0; s < 2; ++s) { acc[s][0] = zero16(); acc[s][1] = zero16(); }
  float mst[2] = {-1e30f, -1e30f}, lst[2] = {0.f, 0.f};

  STAGE(0, 0);
  for (int t = 0; t < NTT; ++t) {
    const int cur = t & 1;
    __syncthreads();                       // staged buf[cur] ready; buf[cur^1] free
    if (t + 1 < NTT) STAGE(cur ^ 1, (t + 1) * KVB);

    // K fragments (A-operand): row kv, swizzled b128 reads
    short8 kf[2][4];
    #pragma unroll
    for (int kvb = 0; kvb < 2; ++kvb)
      #pragma unroll
      for (int kc = 0; kc < 4; ++kc) {
        const int row = kvb * 32 + lo, ch = kc * 2 + hi;
        kf[kvb][kc] = *reinterpret_cast<const short8*>(
            &sK[cur][(row * 8 + (ch ^ (row & 7))) * 8]);
      }

    short8 pa[2][4];
    #pragma unroll
    for (int s = 0; s < 2; ++s) {
      // S^T = K * Q^T : lane holds q=lo, kv rows in regs
      f32x16 st[2];
      #pragma unroll
      for (int kvb = 0; kvb < 2; ++kvb) {
        f32x16 tq = zero16();
        tq = mfma32(kf[kvb][0], qf[s][0], tq);
        tq = mfma32(kf[kvb][1], qf[s][1], tq);
        tq = mfma32(kf[kvb][2], qf[s][2], tq);
        tq = mfma32(kf[kvb][3], qf[s][3], tq);
        st[kvb] = tq;
      }
      // row max: in-register tree + one cross-half swap
      float pm = fmaxf(st[0][0], st[0][1]);
      #pragma unroll
      for (int r = 2; r < 16; ++r) pm = fmaxf(pm, st[0][r]);
      #pragma unroll
      for (int r = 0; r < 16; ++r) pm = fmaxf(pm, st[1][r]);
      pm = fmaxf(pm, __shfl_xor(pm, 32));
      // defer-max: rescale only when max grew by > 8
      if (__any(pm > mst[s] + 8.f)) {
        const float mn = fmaxf(mst[s], pm);
        const float al = __expf(mst[s] - mn);
        mst[s] = mn; lst[s] *= al;
        sBc[wq][s][lo] = al;
        asm volatile("s_waitcnt lgkmcnt(0)" ::: "memory");
        #pragma unroll
        for (int g = 0; g < 4; ++g) {
          const f32x4 a4 = *reinterpret_cast<const f32x4*>(&sBc[wq][s][g * 8 + hi * 4]);
          #pragma unroll
          for (int j = 0; j < 4; ++j) {
            acc[s][0][g * 4 + j] *= a4[j];
            acc[s][1][g * 4 + j] *= a4[j];
          }
        }
      }
      // P = exp(S - m), row sum
      #pragma unroll
      for (int kvb = 0; kvb < 2; ++kvb)
        #pragma unroll
        for (int r = 0; r < 16; ++r)
          st[kvb][r] = __expf(st[kvb][r] - mst[s]);
      {
        const f32x16 sv = st[0] + st[1];
        float sum = ((sv[0] + sv[1]) + (sv[2] + sv[3])) + ((sv[4] + sv[5]) + (sv[6] + sv[7]))
                  + ((sv[8] + sv[9]) + (sv[10] + sv[11])) + ((sv[12] + sv[13]) + (sv[14] + sv[15]));
        sum += __shfl_xor(sum, 32);
        lst[s] += sum;
      }
      // pack P -> bf16 A-fragments via cvt_pk + permlane32_swap
      #pragma unroll
      for (int kvb = 0; kvb < 2; ++kvb)
        #pragma unroll
        for (int f = 0; f < 2; ++f) {
          uint32_t wa = pkbf(st[kvb][f * 8 + 0], st[kvb][f * 8 + 1]);
          uint32_t wb = pkbf(st[kvb][f * 8 + 2], st[kvb][f * 8 + 3]);
          uint32_t wc = pkbf(st[kvb][f * 8 + 4], st[kvb][f * 8 + 5]);
          uint32_t wd = pkbf(st[kvb][f * 8 + 6], st[kvb][f * 8 + 7]);
          asm volatile("v_permlane32_swap_b32 %0, %1" : "+v"(wa), "+v"(wc));
          asm volatile("v_permlane32_swap_b32 %0, %1" : "+v"(wb), "+v"(wd));
          union { uint32_t w[4]; short8 v; } u;
          u.w[0] = wa; u.w[1] = wb; u.w[2] = wc; u.w[3] = wd;
          pa[s][kvb * 2 + f] = u.v;
        }
    }

    // O += P V  (B-operand = V^T rows d)
    #pragma unroll
    for (int db = 0; db < 2; ++db) {
      short8 vb[4];
      #pragma unroll
      for (int k4 = 0; k4 < 4; ++k4) {
        const int row = db * 32 + lo, ch = k4 * 2 + hi;
        vb[k4] = *reinterpret_cast<const short8*>(
            &sVt[cur][(row * 8 + (ch ^ (row & 7))) * 8]);
      }
      #pragma unroll
      for (int s = 0; s < 2; ++s) {
        acc[s][db] = mfma32(pa[s][0], vb[0], acc[s][db]);
        acc[s][db] = mfma32(pa[s][1], vb[1], acc[s][db]);
        acc[s][db] = mfma32(pa[s][2], vb[2], acc[s][db]);
        acc[s][db] = mfma32(pa[s][3], vb[3], acc[s][db]);
      }
    }
  }

  // epilogue: O /= l, write bf16 [8192][1024]
  #pragma unroll
  for (int s = 0; s < 2; ++s) sBc[wq][s][lo] = 1.f / lst[s];
  asm volatile("s_waitcnt lgkmcnt(0)" ::: "memory");
  #pragma unroll
  for (int s = 0; s < 2; ++s)
    #pragma unroll
    for (int g = 0; g < 4; ++g) {
      const f32x4 r4 = *reinterpret_cast<const f32x4*>(&sBc[wq][s][g * 8 + hi * 4]);
      #pragma unroll
      for (int j = 0; j < 4; ++j) {
        const int qrow = q0 + wq * 64 + s * 32 + g * 8 + hi * 4 + j;
        #pragma unroll
        for (int db = 0; db < 2; ++db)
          outp[(size_t)(b * SEQ + qrow) * EMBED + h * 64 + db * 32 + lo] =
              f2bf(acc[s][db][g * 4 + j] * r4[j]);
      }
    }
}

// ---------------- launch ----------------
extern "C" void kernel_launch(void* const* d_in, const int* in_sizes, int n_in,
                              void* d_out, int out_size, void* d_ws, size_t ws_size,
                              hipStream_t stream) {
  const float* x     = (const float*)d_in[0];
  const float* ln1_g = (const float*)d_in[1];
  const float* ln1_b = (const float*)d_in[2];
  const float* qkv_w = (const float*)d_in[3];
  const float* out_w = (const float*)d_in[4];
  const float* out_b = (const float*)d_in[5];
  const float* ln2_g = (const float*)d_in[6];
  const float* ln2_b = (const float*)d_in[7];
  const float* fc1_w = (const float*)d_in[8];
  const float* fc1_b = (const float*)d_in[9];
  const float* fc2_w = (const float*)d_in[10];
  const float* fc2_b = (const float*)d_in[11];
  float* out = (float*)d_out;
  char* ws = (char*)d_ws;

  // workspace layout (bytes)
  ushort* qkvw = (ushort*)(ws);                                   //  6291456
  ushort* outw = (ushort*)(ws + 6291456);                         //  2097152
  ushort* fc1w = (ushort*)(ws + 8388608);                         //  8388608
  ushort* fc2w = (ushort*)(ws + 16777216);                        //  8388608
  float*  x1   = (float*) (ws + 25165824);                        // 33554432
  ushort* hbuf = (ushort*)(ws + 58720256);                        // 16777216
  ushort* qkbuf= (ushort*)(ws + 75497472);                        // 33554432  [8192][2048]
  ushort* vtbuf= (ushort*)(ws + 109051904);                       // 16777216  [1024][8192]
  ushort* obuf = (ushort*)(ws + 125829120);                       // 16777216
  ushort* gbuf = qkbuf;  // gelu buf [8192][4096] reuses qk+vt+o regions (64 MiB)

  cvt_bf16_kernel<<<3072, 256, 0, stream>>>(qkv_w, qkvw, 3 * EMBED * EMBED / 4);
  cvt_bf16_kernel<<<1024, 256, 0, stream>>>(out_w, outw, EMBED * EMBED / 4);
  cvt_bf16_kernel<<<4096, 256, 0, stream>>>(fc1_w, fc1w, HIDDEN * EMBED / 4);
  cvt_bf16_kernel<<<4096, 256, 0, stream>>>(fc2_w, fc2w, EMBED * HIDDEN / 4);

  ln_kernel<<<NTOK, 256, 0, stream>>>(x, ln1_g, ln1_b, hbuf);
  // QK: [8192][2048] = hbuf * Wqk^T   (256x256 tiles, 32x8 = 256 blocks)
  gemm256<0, true><<<256, 512, 0, stream>>>(hbuf, qkvw, nullptr, nullptr,
                                            qkbuf, nullptr, NTOK, 2 * EMBED, EMBED, 32);
  // V^T: [1024][8192] = Wv * hbuf^T   (256x128 tiles, 4x64 = 256 blocks)
  gemm256<0, false><<<256, 512, 0, stream>>>(qkvw + 2048 * 1024, hbuf, nullptr, nullptr,
                                             vtbuf, nullptr, EMBED, NTOK, EMBED, 4);
  attn_kernel<<<dim3(64, 8), 256, 0, stream>>>(qkbuf, vtbuf, obuf);
  // out-proj: (256x128 tiles, 32x8 = 256 blocks)
  gemm256<1, false><<<256, 512, 0, stream>>>(obuf, outw, out_b, x,
                                             nullptr, x1, NTOK, EMBED, EMBED, 32);
  ln_kernel<<<NTOK, 256, 0, stream>>>(x1, ln2_g, ln2_b, hbuf);
  // fc1: (256x256 tiles, 32x16 = 512 blocks)
  gemm256<2, true><<<512, 512, 0, stream>>>(hbuf, fc1w, fc1_b, nullptr,
                                            gbuf, nullptr, NTOK, HIDDEN, EMBED, 32);
  // fc2: (256x128 tiles, 32x8 = 256 blocks)
  gemm256<1, false><<<256, 512, 0, stream>>>(gbuf, fc2w, fc2_b, x1,
                                             nullptr, out, NTOK, EMBED, HIDDEN, 32);
}

// Round 4
// 415.503 us; speedup vs baseline: 1.4934x; 1.0225x over previous
//
#include <hip/hip_runtime.h>
#include <cstdint>

// Transformer block: LN1 -> {QK GEMM, V^T GEMM} -> flash attn (swapped-QK,
// in-register softmax, permlane P re-layout) -> out-proj(+res) -> LN2
// -> fc1(+GELU) -> fc2(+res). All matmuls bf16 MFMA, fp32 accum.
// GEMM: 256-wide tiles, quad-buffered LDS, counted-vmcnt deep pipeline,
// raw s_barrier + setprio; x4 unrolled K-loop with pointer-increment staging
// so all LDS/global addresses are loop-invariant (VALU-bound fix, R3).

using short8 = __attribute__((ext_vector_type(8))) short;
using f32x4  = __attribute__((ext_vector_type(4))) float;
using f32x16 = __attribute__((ext_vector_type(16))) float;

#define EMBED  1024
#define HIDDEN 4096
#define SEQ    2048
#define NTOK   8192   // 4*2048

__device__ __forceinline__ ushort f2bf(float x) {
  union { float f; uint32_t u; } v; v.f = x;
  uint32_t r = v.u + 0x7fffu + ((v.u >> 16) & 1u);   // RNE
  return (ushort)(r >> 16);
}

__device__ __forceinline__ uint32_t pkbf(float lo, float hi) {
  uint32_t r;
  asm("v_cvt_pk_bf16_f32 %0, %1, %2" : "=v"(r) : "v"(lo), "v"(hi));
  return r;
}

__device__ __forceinline__ void gload16(const void* g, void* l) {
  __builtin_amdgcn_global_load_lds((__attribute__((address_space(1))) void*)(g),
                                   (__attribute__((address_space(3))) void*)(l), 16, 0, 0);
}

template<int N> __device__ __forceinline__ void vwait() {
  asm volatile("s_waitcnt vmcnt(%0)" :: "n"(N) : "memory");
}
__device__ __forceinline__ void fence_bar() {
  asm volatile("" ::: "memory");
  __builtin_amdgcn_s_barrier();
  asm volatile("" ::: "memory");
}

__device__ __forceinline__ f32x4 mfma16(short8 a, short8 b, f32x4 c) {
  return __builtin_amdgcn_mfma_f32_16x16x32_bf16(a, b, c, 0, 0, 0);
}
__device__ __forceinline__ f32x16 mfma32(short8 a, short8 b, f32x16 c) {
  return __builtin_amdgcn_mfma_f32_32x32x16_bf16(a, b, c, 0, 0, 0);
}
__device__ __forceinline__ f32x16 zero16() {
  f32x16 z = {0.f,0.f,0.f,0.f,0.f,0.f,0.f,0.f,0.f,0.f,0.f,0.f,0.f,0.f,0.f,0.f};
  return z;
}

// ---------------- fp32 -> bf16 weight conversion ----------------
__global__ __launch_bounds__(256) void cvt_bf16_kernel(const float* __restrict__ in,
                                                       ushort* __restrict__ out, int n4) {
  int i = blockIdx.x * 256 + threadIdx.x;
  if (i < n4) {
    float4 v = reinterpret_cast<const float4*>(in)[i];
    ushort4 o; o.x = f2bf(v.x); o.y = f2bf(v.y); o.z = f2bf(v.z); o.w = f2bf(v.w);
    reinterpret_cast<ushort4*>(out)[i] = o;
  }
}

// ---------------- LayerNorm (fp32 in, bf16 out) ----------------
__global__ __launch_bounds__(256) void ln_kernel(const float* __restrict__ x,
                                                 const float* __restrict__ g,
                                                 const float* __restrict__ b,
                                                 ushort* __restrict__ out) {
  const int row = blockIdx.x, tid = threadIdx.x;
  const float4 xv = reinterpret_cast<const float4*>(x + (size_t)row * EMBED)[tid];
  float s  = xv.x + xv.y + xv.z + xv.w;
  float s2 = xv.x*xv.x + xv.y*xv.y + xv.z*xv.z + xv.w*xv.w;
  #pragma unroll
  for (int off = 32; off >= 1; off >>= 1) { s += __shfl_xor(s, off); s2 += __shfl_xor(s2, off); }
  __shared__ float ps[4], ps2[4];
  if ((tid & 63) == 0) { ps[tid >> 6] = s; ps2[tid >> 6] = s2; }
  __syncthreads();
  s  = ps[0] + ps[1] + ps[2] + ps[3];
  s2 = ps2[0] + ps2[1] + ps2[2] + ps2[3];
  const float mu  = s * (1.f / EMBED);
  const float var = s2 * (1.f / EMBED) - mu * mu;
  const float rs  = rsqrtf(var + 1e-5f);
  const float4 gv = reinterpret_cast<const float4*>(g)[tid];
  const float4 bv = reinterpret_cast<const float4*>(b)[tid];
  ushort4 o;
  o.x = f2bf((xv.x - mu) * rs * gv.x + bv.x);
  o.y = f2bf((xv.y - mu) * rs * gv.y + bv.y);
  o.z = f2bf((xv.z - mu) * rs * gv.z + bv.z);
  o.w = f2bf((xv.w - mu) * rs * gv.w + bv.w);
  reinterpret_cast<ushort4*>(out + (size_t)row * EMBED)[tid] = o;
}

// ---------------- bf16 GEMM: C[M,N] = A[M,K] * B[N,K]^T (+epilogue) ----------------
// SQ=true: 256x256 tile (8 waves 2Mx4N). SQ=false: 256x128 tile (8 waves 4Mx2N).
// Quad-buffered BK=32 tiles; stage tile u+3 during tile u; counted vmcnt; x4 unroll.
template<int EPI, bool SQ>
__global__ __launch_bounds__(512) void gemm256(const ushort* __restrict__ A,
                                               const ushort* __restrict__ B,
                                               const float* __restrict__ bias,
                                               const float* __restrict__ res,
                                               ushort* __restrict__ outb,
                                               float* __restrict__ outf,
                                               int M, int N, int K, int gx) {
  constexpr int BN   = SQ ? 256 : 128;
  constexpr int MP   = SQ ? 8 : 4;          // 16-row m-positions per wave
  constexpr int NPH  = SQ ? 2 : 1;          // phases per K-tile
  constexpr int LPT  = SQ ? 4 : 3;          // gload16 rounds per tile per thread
  constexpr int NB   = LPT - 2;             // B staging rounds
  constexpr int ABUF = 256 * 32;            // ushorts
  constexpr int BBUF = BN * 32;
  __shared__ ushort lds[4][ABUF + BBUF];

  const int nwg = gridDim.x;                // nwg % 8 == 0 for all our shapes
  const int b0  = blockIdx.x;
  const int bid = (b0 & 7) * (nwg >> 3) + (b0 >> 3);   // XCD-chunked swizzle
  const int m0  = (bid % gx) * 256;
  const int n0  = (bid / gx) * BN;

  const int tid = threadIdx.x, lane = tid & 63, wave = tid >> 6;
  const int wm = (SQ ? (wave >> 2) : (wave >> 1)) * (MP * 16);
  const int wn = (SQ ? (wave & 3) : (wave & 1)) * 64;
  const int l15 = lane & 15, l4 = lane >> 4;
  const int NT = K >> 5;                    // divisible by 4 for all our shapes

  // per-thread staging source pointers; advance +32 elems per staged tile
  const ushort* aSrc[2];
  const ushort* bSrc[NB];
  #pragma unroll
  for (int rd = 0; rd < 2; ++rd) {
    const int slot = rd * 512 + tid;
    const int r = slot >> 2;
    const int cs = (slot & 3) ^ ((r >> 1) & 3);
    aSrc[rd] = A + (size_t)(m0 + r) * K + cs * 8;
  }
  #pragma unroll
  for (int rd = 0; rd < NB; ++rd) {
    const int slot = rd * 512 + tid;
    const int r = slot >> 2;
    const int cs = (slot & 3) ^ ((r >> 1) & 3);
    bSrc[rd] = B + (size_t)(n0 + r) * K + cs * 8;
  }
  auto stageA = [&](int buf, int rd) { gload16(aSrc[rd], &lds[buf][(rd * 512 + tid) * 8]); };
  auto stageB = [&](int buf, int rd) { gload16(bSrc[rd], &lds[buf][ABUF + (rd * 512 + tid) * 8]); };
  auto advance = [&]() {
    #pragma unroll
    for (int rd = 0; rd < 2; ++rd) aSrc[rd] += 32;
    #pragma unroll
    for (int rd = 0; rd < NB; ++rd) bSrc[rd] += 32;
  };

  // prologue: stage tiles 0..2 into bufs 0..2
  #pragma unroll
  for (int t = 0; t < 3; ++t) {
    stageA(t, 0); stageA(t, 1);
    #pragma unroll
    for (int rd = 0; rd < NB; ++rd) stageB(t, rd);
    advance();
  }
  vwait<2 * LPT>();               // tile 0 resident; 2 tiles stay in flight
  fence_bar();

  f32x4 acc[MP][4] = {};

  // one K-tile; q = buffer index (compile-time at every call site),
  // st = stage tile u+3, wsel: 0 -> vwait(2LPT), 1 -> vwait(LPT), 2 -> vwait(0), 3 -> none
  auto doTile = [&](int q, bool st, int wsel) {
    const ushort* bA = &lds[q][0];
    const ushort* bB = &lds[q][ABUF];
    const int sbuf = (q + 3) & 3;
    short8 bf[4];
    #pragma unroll
    for (int j = 0; j < 4; ++j) {
      const int rb = wn + j * 16 + l15;
      bf[j] = *reinterpret_cast<const short8*>(&bB[rb * 32 + ((l4 ^ ((rb >> 1) & 3)) * 8)]);
    }
    #pragma unroll
    for (int ph = 0; ph < NPH; ++ph) {
      short8 af[4];
      #pragma unroll
      for (int i = 0; i < 4; ++i) {
        const int ra = wm + (ph * 4 + i) * 16 + l15;
        af[i] = *reinterpret_cast<const short8*>(&bA[ra * 32 + ((l4 ^ ((ra >> 1) & 3)) * 8)]);
      }
      if (st) {
        if constexpr (SQ) {
          if (ph == 0) { stageA(sbuf, 0); stageA(sbuf, 1); }
          else         { stageB(sbuf, 0); stageB(sbuf, 1); }
        } else {
          stageA(sbuf, 0); stageA(sbuf, 1); stageB(sbuf, 0);
        }
      }
      fence_bar();
      __builtin_amdgcn_s_setprio(1);
      #pragma unroll
      for (int i = 0; i < 4; ++i)
        #pragma unroll
        for (int j = 0; j < 4; ++j)
          acc[ph * 4 + i][j] = mfma16(af[i], bf[j], acc[ph * 4 + i][j]);
      __builtin_amdgcn_s_setprio(0);
      if (ph == NPH - 1) {        // tile boundary: next tile must be resident
        if (st) advance();
        if (wsel == 0)      vwait<2 * LPT>();
        else if (wsel == 1) vwait<LPT>();
        else if (wsel == 2) vwait<0>();
      }
      fence_bar();
    }
  };

  for (int u0 = 0; u0 < NT - 4; u0 += 4) {
    doTile(0, true, 0); doTile(1, true, 0); doTile(2, true, 0); doTile(3, true, 0);
  }
  // tail: u = NT-4 .. NT-1
  doTile(0, true, 0); doTile(1, false, 1); doTile(2, false, 2); doTile(3, false, 3);

  #pragma unroll
  for (int i = 0; i < MP; ++i)
    #pragma unroll
    for (int j = 0; j < 4; ++j)
      #pragma unroll
      for (int r = 0; r < 4; ++r) {
        const int row = m0 + wm + i * 16 + l4 * 4 + r;
        const int col = n0 + wn + j * 16 + l15;
        const size_t idx = (size_t)row * N + col;
        float v = acc[i][j][r];
        if constexpr (EPI == 0) {
          outb[idx] = f2bf(v);
        } else if constexpr (EPI == 1) {
          outf[idx] = v + bias[col] + res[idx];
        } else {
          v += bias[col];
          v = 0.5f * v * (1.f + erff(v * 0.70710678118654752f));
          outb[idx] = f2bf(v);
        }
      }
}

// ---------------- flash attention, swapped-QK in-register softmax ----------------
// grid (B*H=64, SEQ/256=8), block 256 (4 waves). Wave: 64 q rows (2 sets of 32).
// qk: [8192][2048] bf16 (q at col h*64, k at col 1024+h*64). vt: [1024][8192] bf16.
// No 1/sqrt(d) scaling (per reference).
#define KVB 64
#define NTT (SEQ / KVB)

__global__ __launch_bounds__(256, 2) void attn_kernel(const ushort* __restrict__ qk,
                                                      const ushort* __restrict__ vt,
                                                      ushort* __restrict__ outp) {
  const int tid = threadIdx.x, lane = tid & 63, wq = tid >> 6;
  const int hi = lane >> 5, lo = lane & 31;
  const int b = blockIdx.x >> 4, h = blockIdx.x & 15;
  const int q0 = blockIdx.y * 256;

  __shared__ ushort sK[2][64 * 64];
  __shared__ ushort sVt[2][64 * 64];
  __shared__ float sBc[4][2][32];

  // Q fragments (B-operand): row q, k-chunk (hi*8) within kc*16
  short8 qf[2][4];
  #pragma unroll
  for (int s = 0; s < 2; ++s)
    #pragma unroll
    for (int kc = 0; kc < 4; ++kc)
      qf[s][kc] = *reinterpret_cast<const short8*>(
          qk + (size_t)(b * SEQ + q0 + wq * 64 + s * 32 + lo) * 2048 + h * 64 + kc * 16 + hi * 8);

  auto STAGE = [&](int bb, int kt) {
    #pragma unroll
    for (int i = 0; i < 2; ++i) {
      const int slot = i * 256 + tid;
      const int r = slot >> 3;
      const int c = (slot & 7) ^ (r & 7);           // inverse-swizzled source chunk
      gload16(qk + (size_t)(b * SEQ + kt + r) * 2048 + 1024 + h * 64 + c * 8,
              &sK[bb][(i * 256 + wq * 64) * 8]);
      gload16(vt + (size_t)(h * 64 + r) * 8192 + b * SEQ + kt + c * 8,
              &sVt[bb][(i * 256 + wq * 64) * 8]);
    }
  };

  f32x16 acc[2][2];
  #pragma unroll
  for (int s = 0; s < 2; ++s) { acc[s][0] = zero16(); acc[s][1] = zero16(); }
  float mst[2] = {-1e30f, -1e30f}, lst[2] = {0.f, 0.f};

  STAGE(0, 0);
  for (int t = 0; t < NTT; ++t) {
    const int cur = t & 1;
    __syncthreads();                       // staged buf[cur] ready; buf[cur^1] free
    if (t + 1 < NTT) STAGE(cur ^ 1, (t + 1) * KVB);

    // K fragments (A-operand): row kv, swizzled b128 reads
    short8 kf[2][4];
    #pragma unroll
    for (int kvb = 0; kvb < 2; ++kvb)
      #pragma unroll
      for (int kc = 0; kc < 4; ++kc) {
        const int row = kvb * 32 + lo, ch = kc * 2 + hi;
        kf[kvb][kc] = *reinterpret_cast<const short8*>(
            &sK[cur][(row * 8 + (ch ^ (row & 7))) * 8]);
      }

    short8 pa[2][4];
    #pragma unroll
    for (int s = 0; s < 2; ++s) {
      // S^T = K * Q^T : lane holds q=lo, kv rows in regs
      f32x16 st[2];
      #pragma unroll
      for (int kvb = 0; kvb < 2; ++kvb) {
        f32x16 tq = zero16();
        tq = mfma32(kf[kvb][0], qf[s][0], tq);
        tq = mfma32(kf[kvb][1], qf[s][1], tq);
        tq = mfma32(kf[kvb][2], qf[s][2], tq);
        tq = mfma32(kf[kvb][3], qf[s][3], tq);
        st[kvb] = tq;
      }
      // row max: in-register tree + one cross-half swap
      float pm = fmaxf(st[0][0], st[0][1]);
      #pragma unroll
      for (int r = 2; r < 16; ++r) pm = fmaxf(pm, st[0][r]);
      #pragma unroll
      for (int r = 0; r < 16; ++r) pm = fmaxf(pm, st[1][r]);
      pm = fmaxf(pm, __shfl_xor(pm, 32));
      // defer-max: rescale only when max grew by > 8
      if (__any(pm > mst[s] + 8.f)) {
        const float mn = fmaxf(mst[s], pm);
        const float al = __expf(mst[s] - mn);
        mst[s] = mn; lst[s] *= al;
        sBc[wq][s][lo] = al;
        asm volatile("s_waitcnt lgkmcnt(0)" ::: "memory");
        #pragma unroll
        for (int g = 0; g < 4; ++g) {
          const f32x4 a4 = *reinterpret_cast<const f32x4*>(&sBc[wq][s][g * 8 + hi * 4]);
          #pragma unroll
          for (int j = 0; j < 4; ++j) {
            acc[s][0][g * 4 + j] *= a4[j];
            acc[s][1][g * 4 + j] *= a4[j];
          }
        }
      }
      // P = exp(S - m), row sum
      #pragma unroll
      for (int kvb = 0; kvb < 2; ++kvb)
        #pragma unroll
        for (int r = 0; r < 16; ++r)
          st[kvb][r] = __expf(st[kvb][r] - mst[s]);
      {
        const f32x16 sv = st[0] + st[1];
        float sum = ((sv[0] + sv[1]) + (sv[2] + sv[3])) + ((sv[4] + sv[5]) + (sv[6] + sv[7]))
                  + ((sv[8] + sv[9]) + (sv[10] + sv[11])) + ((sv[12] + sv[13]) + (sv[14] + sv[15]));
        sum += __shfl_xor(sum, 32);
        lst[s] += sum;
      }
      // pack P -> bf16 A-fragments via cvt_pk + permlane32_swap
      #pragma unroll
      for (int kvb = 0; kvb < 2; ++kvb)
        #pragma unroll
        for (int f = 0; f < 2; ++f) {
          uint32_t wa = pkbf(st[kvb][f * 8 + 0], st[kvb][f * 8 + 1]);
          uint32_t wb = pkbf(st[kvb][f * 8 + 2], st[kvb][f * 8 + 3]);
          uint32_t wc = pkbf(st[kvb][f * 8 + 4], st[kvb][f * 8 + 5]);
          uint32_t wd = pkbf(st[kvb][f * 8 + 6], st[kvb][f * 8 + 7]);
          asm volatile("v_permlane32_swap_b32 %0, %1" : "+v"(wa), "+v"(wc));
          asm volatile("v_permlane32_swap_b32 %0, %1" : "+v"(wb), "+v"(wd));
          union { uint32_t w[4]; short8 v; } u;
          u.w[0] = wa; u.w[1] = wb; u.w[2] = wc; u.w[3] = wd;
          pa[s][kvb * 2 + f] = u.v;
        }
    }

    // O += P V  (B-operand = V^T rows d)
    #pragma unroll
    for (int db = 0; db < 2; ++db) {
      short8 vb[4];
      #pragma unroll
      for (int k4 = 0; k4 < 4; ++k4) {
        const int row = db * 32 + lo, ch = k4 * 2 + hi;
        vb[k4] = *reinterpret_cast<const short8*>(
            &sVt[cur][(row * 8 + (ch ^ (row & 7))) * 8]);
      }
      #pragma unroll
      for (int s = 0; s < 2; ++s) {
        acc[s][db] = mfma32(pa[s][0], vb[0], acc[s][db]);
        acc[s][db] = mfma32(pa[s][1], vb[1], acc[s][db]);
        acc[s][db] = mfma32(pa[s][2], vb[2], acc[s][db]);
        acc[s][db] = mfma32(pa[s][3], vb[3], acc[s][db]);
      }
    }
  }

  // epilogue: O /= l, write bf16 [8192][1024]
  #pragma unroll
  for (int s = 0; s < 2; ++s) sBc[wq][s][lo] = 1.f / lst[s];
  asm volatile("s_waitcnt lgkmcnt(0)" ::: "memory");
  #pragma unroll
  for (int s = 0; s < 2; ++s)
    #pragma unroll
    for (int g = 0; g < 4; ++g) {
      const f32x4 r4 = *reinterpret_cast<const f32x4*>(&sBc[wq][s][g * 8 + hi * 4]);
      #pragma unroll
      for (int j = 0; j < 4; ++j) {
        const int qrow = q0 + wq * 64 + s * 32 + g * 8 + hi * 4 + j;
        #pragma unroll
        for (int db = 0; db < 2; ++db)
          outp[(size_t)(b * SEQ + qrow) * EMBED + h * 64 + db * 32 + lo] =
              f2bf(acc[s][db][g * 4 + j] * r4[j]);
      }
    }
}

// ---------------- launch ----------------
extern "C" void kernel_launch(void* const* d_in, const int* in_sizes, int n_in,
                              void* d_out, int out_size, void* d_ws, size_t ws_size,
                              hipStream_t stream) {
  const float* x     = (const float*)d_in[0];
  const float* ln1_g = (const float*)d_in[1];
  const float* ln1_b = (const float*)d_in[2];
  const float* qkv_w = (const float*)d_in[3];
  const float* out_w = (const float*)d_in[4];
  const float* out_b = (const float*)d_in[5];
  const float* ln2_g = (const float*)d_in[6];
  const float* ln2_b = (const float*)d_in[7];
  const float* fc1_w = (const float*)d_in[8];
  const float* fc1_b = (const float*)d_in[9];
  const float* fc2_w = (const float*)d_in[10];
  const float* fc2_b = (const float*)d_in[11];
  float* out = (float*)d_out;
  char* ws = (char*)d_ws;

  // workspace layout (bytes)
  ushort* qkvw = (ushort*)(ws);                                   //  6291456
  ushort* outw = (ushort*)(ws + 6291456);                         //  2097152
  ushort* fc1w = (ushort*)(ws + 8388608);                         //  8388608
  ushort* fc2w = (ushort*)(ws + 16777216);                        //  8388608
  float*  x1   = (float*) (ws + 25165824);                        // 33554432
  ushort* hbuf = (ushort*)(ws + 58720256);                        // 16777216
  ushort* qkbuf= (ushort*)(ws + 75497472);                        // 33554432  [8192][2048]
  ushort* vtbuf= (ushort*)(ws + 109051904);                       // 16777216  [1024][8192]
  ushort* obuf = (ushort*)(ws + 125829120);                       // 16777216
  ushort* gbuf = qkbuf;  // gelu buf [8192][4096] reuses qk+vt+o regions (64 MiB)

  cvt_bf16_kernel<<<3072, 256, 0, stream>>>(qkv_w, qkvw, 3 * EMBED * EMBED / 4);
  cvt_bf16_kernel<<<1024, 256, 0, stream>>>(out_w, outw, EMBED * EMBED / 4);
  cvt_bf16_kernel<<<4096, 256, 0, stream>>>(fc1_w, fc1w, HIDDEN * EMBED / 4);
  cvt_bf16_kernel<<<4096, 256, 0, stream>>>(fc2_w, fc2w, EMBED * HIDDEN / 4);

  ln_kernel<<<NTOK, 256, 0, stream>>>(x, ln1_g, ln1_b, hbuf);
  // QK: [8192][2048] = hbuf * Wqk^T   (256x256 tiles, 32x8 = 256 blocks)
  gemm256<0, true><<<256, 512, 0, stream>>>(hbuf, qkvw, nullptr, nullptr,
                                            qkbuf, nullptr, NTOK, 2 * EMBED, EMBED, 32);
  // V^T: [1024][8192] = Wv * hbuf^T   (256x128 tiles, 4x64 = 256 blocks)
  gemm256<0, false><<<256, 512, 0, stream>>>(qkvw + 2048 * 1024, hbuf, nullptr, nullptr,
                                             vtbuf, nullptr, EMBED, NTOK, EMBED, 4);
  attn_kernel<<<dim3(64, 8), 256, 0, stream>>>(qkbuf, vtbuf, obuf);
  // out-proj: (256x128 tiles, 32x8 = 256 blocks)
  gemm256<1, false><<<256, 512, 0, stream>>>(obuf, outw, out_b, x,
                                             nullptr, x1, NTOK, EMBED, EMBED, 32);
  ln_kernel<<<NTOK, 256, 0, stream>>>(x1, ln2_g, ln2_b, hbuf);
  // fc1: (256x256 tiles, 32x16 = 512 blocks)
  gemm256<2, true><<<512, 512, 0, stream>>>(hbuf, fc1w, fc1_b, nullptr,
                                            gbuf, nullptr, NTOK, HIDDEN, EMBED, 32);
  // fc2: (256x128 tiles, 32x8 = 256 blocks)
  gemm256<1, false><<<256, 512, 0, stream>>>(gbuf, fc2w, fc2_b, x1,
                                             nullptr, out, NTOK, EMBED, HIDDEN, 32);
}

// Round 5
// 411.324 us; speedup vs baseline: 1.5085x; 1.0102x over previous
//
#include <hip/hip_runtime.h>
#include <cstdint>

// Transformer block: LN1 -> {QK GEMM, V^T GEMM} -> flash attn (swapped-QK,
// in-register softmax, permlane P re-layout) -> out-proj(+res) -> LN2
// -> fc1(+GELU) -> fc2(+res). All matmuls bf16 MFMA, fp32 accum.
// GEMM (R5): BK=64 double-buffered, K-half staging (1 half-tile per phase),
// counted vmcnt every phase-pair (never 0 in steady state) — true 8-phase
// discipline per m201/m218 (loads span >=2 phases between issue and wait).

using short8 = __attribute__((ext_vector_type(8))) short;
using f32x4  = __attribute__((ext_vector_type(4))) float;
using f32x16 = __attribute__((ext_vector_type(16))) float;

#define EMBED  1024
#define HIDDEN 4096
#define SEQ    2048
#define NTOK   8192   // 4*2048

__device__ __forceinline__ ushort f2bf(float x) {
  union { float f; uint32_t u; } v; v.f = x;
  uint32_t r = v.u + 0x7fffu + ((v.u >> 16) & 1u);   // RNE
  return (ushort)(r >> 16);
}

__device__ __forceinline__ uint32_t pkbf(float lo, float hi) {
  uint32_t r;
  asm("v_cvt_pk_bf16_f32 %0, %1, %2" : "=v"(r) : "v"(lo), "v"(hi));
  return r;
}

__device__ __forceinline__ void gload16(const void* g, void* l) {
  __builtin_amdgcn_global_load_lds((__attribute__((address_space(1))) void*)(g),
                                   (__attribute__((address_space(3))) void*)(l), 16, 0, 0);
}

template<int N> __device__ __forceinline__ void vwait() {
  asm volatile("s_waitcnt vmcnt(%0)" :: "n"(N) : "memory");
}
__device__ __forceinline__ void fence_bar() {
  asm volatile("" ::: "memory");
  __builtin_amdgcn_s_barrier();
  asm volatile("" ::: "memory");
}

__device__ __forceinline__ f32x4 mfma16(short8 a, short8 b, f32x4 c) {
  return __builtin_amdgcn_mfma_f32_16x16x32_bf16(a, b, c, 0, 0, 0);
}
__device__ __forceinline__ f32x16 mfma32(short8 a, short8 b, f32x16 c) {
  return __builtin_amdgcn_mfma_f32_32x32x16_bf16(a, b, c, 0, 0, 0);
}
__device__ __forceinline__ f32x16 zero16() {
  f32x16 z = {0.f,0.f,0.f,0.f,0.f,0.f,0.f,0.f,0.f,0.f,0.f,0.f,0.f,0.f,0.f,0.f};
  return z;
}

// ---------------- fp32 -> bf16 weight conversion ----------------
__global__ __launch_bounds__(256) void cvt_bf16_kernel(const float* __restrict__ in,
                                                       ushort* __restrict__ out, int n4) {
  int i = blockIdx.x * 256 + threadIdx.x;
  if (i < n4) {
    float4 v = reinterpret_cast<const float4*>(in)[i];
    ushort4 o; o.x = f2bf(v.x); o.y = f2bf(v.y); o.z = f2bf(v.z); o.w = f2bf(v.w);
    reinterpret_cast<ushort4*>(out)[i] = o;
  }
}

// ---------------- LayerNorm (fp32 in, bf16 out) ----------------
__global__ __launch_bounds__(256) void ln_kernel(const float* __restrict__ x,
                                                 const float* __restrict__ g,
                                                 const float* __restrict__ b,
                                                 ushort* __restrict__ out) {
  const int row = blockIdx.x, tid = threadIdx.x;
  const float4 xv = reinterpret_cast<const float4*>(x + (size_t)row * EMBED)[tid];
  float s  = xv.x + xv.y + xv.z + xv.w;
  float s2 = xv.x*xv.x + xv.y*xv.y + xv.z*xv.z + xv.w*xv.w;
  #pragma unroll
  for (int off = 32; off >= 1; off >>= 1) { s += __shfl_xor(s, off); s2 += __shfl_xor(s2, off); }
  __shared__ float ps[4], ps2[4];
  if ((tid & 63) == 0) { ps[tid >> 6] = s; ps2[tid >> 6] = s2; }
  __syncthreads();
  s  = ps[0] + ps[1] + ps[2] + ps[3];
  s2 = ps2[0] + ps2[1] + ps2[2] + ps2[3];
  const float mu  = s * (1.f / EMBED);
  const float var = s2 * (1.f / EMBED) - mu * mu;
  const float rs  = rsqrtf(var + 1e-5f);
  const float4 gv = reinterpret_cast<const float4*>(g)[tid];
  const float4 bv = reinterpret_cast<const float4*>(b)[tid];
  ushort4 o;
  o.x = f2bf((xv.x - mu) * rs * gv.x + bv.x);
  o.y = f2bf((xv.y - mu) * rs * gv.y + bv.y);
  o.z = f2bf((xv.z - mu) * rs * gv.z + bv.z);
  o.w = f2bf((xv.w - mu) * rs * gv.w + bv.w);
  reinterpret_cast<ushort4*>(out + (size_t)row * EMBED)[tid] = o;
}

// ---------------- bf16 GEMM: C[M,N] = A[M,K] * B[N,K]^T (+epilogue) ----------------
// SQ=true: 256x256 tile (8 waves 2Mx4N, wave out 128x64), 4 phases/tile.
// SQ=false: 256x128 tile (8 waves 4Mx2N, wave out 64x64), 2 phases/tile.
// BK=64 double-buffered as 4 K-half-tiles {A,B}x{klo,khi}; stage 1(SQ)/2(SK)
// halves per phase for tile t+1 while computing t; counted vwait(4)/(3) per
// phase-pair so loads stay in flight >=2 phases. Never vmcnt(0) in steady state.
template<int EPI, bool SQ>
__global__ __launch_bounds__(512) void gemm64(const ushort* __restrict__ A,
                                              const ushort* __restrict__ B,
                                              const float* __restrict__ bias,
                                              const float* __restrict__ res,
                                              ushort* __restrict__ outb,
                                              float* __restrict__ outf,
                                              int M, int N, int K, int gx) {
  constexpr int BN  = SQ ? 256 : 128;
  constexpr int MP  = SQ ? 8 : 4;           // 16-row m-positions per wave
  constexpr int NBR = SQ ? 2 : 1;           // B staging rounds per half
  constexpr int AH  = 256 * 32;             // ushorts per A K-half
  constexpr int BH  = BN * 32;              // ushorts per B K-half
  constexpr int KH  = AH + BH;              // one K-half (A+B)
  __shared__ ushort lds[2][2 * KH];
  // region offsets within a buffer: h0(A,klo)=0, h1(B,klo)=AH, h2(A,khi)=KH, h3(B,khi)=KH+AH

  const int nwg = gridDim.x;                // nwg % 8 == 0 for all our shapes
  const int b0  = blockIdx.x;
  const int bid = (b0 & 7) * (nwg >> 3) + (b0 >> 3);   // XCD-chunked swizzle
  const int m0  = (bid % gx) * 256;
  const int n0  = (bid / gx) * BN;

  const int tid = threadIdx.x, lane = tid & 63, wave = tid >> 6;
  const int wm = (SQ ? (wave >> 2) : (wave >> 1)) * (MP * 16);
  const int wn = (SQ ? (wave & 3) : (wave & 1)) * 64;
  const int l15 = lane & 15, l4 = lane >> 4;
  const int NT = K >> 6;                    // BK=64; NT even for all our shapes

  // staging source pointers (advance +64 elems per tile); half k-offset = +32
  const ushort* aS[2];
  const ushort* bS[NBR];
  #pragma unroll
  for (int rd = 0; rd < 2; ++rd) {
    const int slot = rd * 512 + tid;
    const int r = slot >> 2;
    const int cs = (slot & 3) ^ ((r >> 1) & 3);
    aS[rd] = A + (size_t)(m0 + r) * K + cs * 8;
  }
  #pragma unroll
  for (int rd = 0; rd < NBR; ++rd) {
    const int slot = rd * 512 + tid;
    const int r = slot >> 2;
    const int cs = (slot & 3) ^ ((r >> 1) & 3);
    bS[rd] = B + (size_t)(n0 + r) * K + cs * 8;
  }
  auto stA = [&](ushort* buf, int half, int rd) {
    gload16(aS[rd] + half * 32, buf + half * KH + (rd * 512 + tid) * 8);
  };
  auto stB = [&](ushort* buf, int half, int rd) {
    gload16(bS[rd] + half * 32, buf + AH + half * KH + (rd * 512 + tid) * 8);
  };
  auto advance = [&]() {
    #pragma unroll
    for (int rd = 0; rd < 2; ++rd) aS[rd] += 64;
    #pragma unroll
    for (int rd = 0; rd < NBR; ++rd) bS[rd] += 64;
  };

  // per-thread fragment offsets (ushort units) within an A/B K-half region
  int aOff[MP], bOff[4];
  #pragma unroll
  for (int i = 0; i < MP; ++i) {
    const int ra = wm + i * 16 + l15;
    aOff[i] = ra * 32 + ((l4 ^ ((ra >> 1) & 3)) * 8);
  }
  #pragma unroll
  for (int j = 0; j < 4; ++j) {
    const int rb = wn + j * 16 + l15;
    bOff[j] = rb * 32 + ((l4 ^ ((rb >> 1) & 3)) * 8);
  }

  // prologue: stage tile 0 halves h0..h3 (issue order matters for the ledger)
  ushort* p0 = &lds[0][0];
  ushort* p1 = &lds[1][0];
  stA(p0, 0, 0); stA(p0, 0, 1);
  #pragma unroll
  for (int rd = 0; rd < NBR; ++rd) stB(p0, 0, rd);
  stA(p0, 1, 0); stA(p0, 1, 1);
  #pragma unroll
  for (int rd = 0; rd < NBR; ++rd) stB(p0, 1, rd);
  advance();
  vwait<SQ ? 4 : 3>();            // h0,h1 of tile0 resident; h2,h3 in flight
  fence_bar();

  f32x4 acc[MP][4] = {};

  // one BK=64 tile on buffer `cur`, staging tile t+1 into `nxt` when st.
  auto TILE = [&](ushort* cur, ushort* nxt, bool st, bool tail) {
    short8 af[4], bf[4];
    if constexpr (SQ) {
      // ---- ph0: k-lo, m-frags 0-3 ----
      #pragma unroll
      for (int j = 0; j < 4; ++j) bf[j] = *reinterpret_cast<const short8*>(cur + AH + bOff[j]);
      #pragma unroll
      for (int i = 0; i < 4; ++i) af[i] = *reinterpret_cast<const short8*>(cur + aOff[i]);
      if (st) { stA(nxt, 0, 0); stA(nxt, 0, 1); }
      fence_bar();
      __builtin_amdgcn_s_setprio(1);
      #pragma unroll
      for (int i = 0; i < 4; ++i)
        #pragma unroll
        for (int j = 0; j < 4; ++j) acc[i][j] = mfma16(af[i], bf[j], acc[i][j]);
      __builtin_amdgcn_s_setprio(0);
      fence_bar();
      // ---- ph1: k-lo, m-frags 4-7 ----
      #pragma unroll
      for (int i = 0; i < 4; ++i) af[i] = *reinterpret_cast<const short8*>(cur + aOff[4 + i]);
      if (st) { stB(nxt, 0, 0); stB(nxt, 0, 1); }
      fence_bar();
      __builtin_amdgcn_s_setprio(1);
      #pragma unroll
      for (int i = 0; i < 4; ++i)
        #pragma unroll
        for (int j = 0; j < 4; ++j) acc[4 + i][j] = mfma16(af[i], bf[j], acc[4 + i][j]);
      __builtin_amdgcn_s_setprio(0);
      if (!tail) vwait<4>(); else vwait<0>();   // k-hi halves of current tile resident
      fence_bar();
      // ---- ph2: k-hi, m-frags 0-3 ----
      #pragma unroll
      for (int j = 0; j < 4; ++j) bf[j] = *reinterpret_cast<const short8*>(cur + KH + AH + bOff[j]);
      #pragma unroll
      for (int i = 0; i < 4; ++i) af[i] = *reinterpret_cast<const short8*>(cur + KH + aOff[i]);
      if (st) { stA(nxt, 1, 0); stA(nxt, 1, 1); }
      fence_bar();
      __builtin_amdgcn_s_setprio(1);
      #pragma unroll
      for (int i = 0; i < 4; ++i)
        #pragma unroll
        for (int j = 0; j < 4; ++j) acc[i][j] = mfma16(af[i], bf[j], acc[i][j]);
      __builtin_amdgcn_s_setprio(0);
      fence_bar();
      // ---- ph3: k-hi, m-frags 4-7 ----
      #pragma unroll
      for (int i = 0; i < 4; ++i) af[i] = *reinterpret_cast<const short8*>(cur + KH + aOff[4 + i]);
      if (st) { stB(nxt, 1, 0); stB(nxt, 1, 1); }
      fence_bar();
      __builtin_amdgcn_s_setprio(1);
      #pragma unroll
      for (int i = 0; i < 4; ++i)
        #pragma unroll
        for (int j = 0; j < 4; ++j) acc[4 + i][j] = mfma16(af[i], bf[j], acc[4 + i][j]);
      __builtin_amdgcn_s_setprio(0);
      if (!tail) vwait<4>();                    // k-lo halves of next tile resident
      fence_bar();
    } else {
      // ---- ph0: k-lo, all frags ----
      #pragma unroll
      for (int j = 0; j < 4; ++j) bf[j] = *reinterpret_cast<const short8*>(cur + AH + bOff[j]);
      #pragma unroll
      for (int i = 0; i < 4; ++i) af[i] = *reinterpret_cast<const short8*>(cur + aOff[i]);
      if (st) { stA(nxt, 0, 0); stA(nxt, 0, 1); stB(nxt, 0, 0); }
      fence_bar();
      __builtin_amdgcn_s_setprio(1);
      #pragma unroll
      for (int i = 0; i < 4; ++i)
        #pragma unroll
        for (int j = 0; j < 4; ++j) acc[i][j] = mfma16(af[i], bf[j], acc[i][j]);
      __builtin_amdgcn_s_setprio(0);
      if (!tail) vwait<3>(); else vwait<0>();
      fence_bar();
      // ---- ph1: k-hi, all frags ----
      #pragma unroll
      for (int j = 0; j < 4; ++j) bf[j] = *reinterpret_cast<const short8*>(cur + KH + AH + bOff[j]);
      #pragma unroll
      for (int i = 0; i < 4; ++i) af[i] = *reinterpret_cast<const short8*>(cur + KH + aOff[i]);
      if (st) { stA(nxt, 1, 0); stA(nxt, 1, 1); stB(nxt, 1, 0); }
      fence_bar();
      __builtin_amdgcn_s_setprio(1);
      #pragma unroll
      for (int i = 0; i < 4; ++i)
        #pragma unroll
        for (int j = 0; j < 4; ++j) acc[i][j] = mfma16(af[i], bf[j], acc[i][j]);
      __builtin_amdgcn_s_setprio(0);
      if (!tail) vwait<3>();
      fence_bar();
    }
    if (st) advance();
  };

  for (int t = 0; t < NT - 2; t += 2) { TILE(p0, p1, true, false); TILE(p1, p0, true, false); }
  TILE(p0, p1, true, false);
  TILE(p1, p0, false, true);

  #pragma unroll
  for (int i = 0; i < MP; ++i)
    #pragma unroll
    for (int j = 0; j < 4; ++j)
      #pragma unroll
      for (int r = 0; r < 4; ++r) {
        const int row = m0 + wm + i * 16 + l4 * 4 + r;
        const int col = n0 + wn + j * 16 + l15;
        const size_t idx = (size_t)row * N + col;
        float v = acc[i][j][r];
        if constexpr (EPI == 0) {
          outb[idx] = f2bf(v);
        } else if constexpr (EPI == 1) {
          outf[idx] = v + bias[col] + res[idx];
        } else {
          v += bias[col];
          v = 0.5f * v * (1.f + erff(v * 0.70710678118654752f));
          outb[idx] = f2bf(v);
        }
      }
}

// ---------------- flash attention, swapped-QK in-register softmax ----------------
// grid (B*H=64, SEQ/256=8), block 256 (4 waves). Wave: 64 q rows (2 sets of 32).
// qk: [8192][2048] bf16 (q at col h*64, k at col 1024+h*64). vt: [1024][8192] bf16.
// No 1/sqrt(d) scaling (per reference).
#define KVB 64
#define NTT (SEQ / KVB)

__global__ __launch_bounds__(256, 2) void attn_kernel(const ushort* __restrict__ qk,
                                                      const ushort* __restrict__ vt,
                                                      ushort* __restrict__ outp) {
  const int tid = threadIdx.x, lane = tid & 63, wq = tid >> 6;
  const int hi = lane >> 5, lo = lane & 31;
  const int b = blockIdx.x >> 4, h = blockIdx.x & 15;
  const int q0 = blockIdx.y * 256;

  __shared__ ushort sK[2][64 * 64];
  __shared__ ushort sVt[2][64 * 64];
  __shared__ float sBc[4][2][32];

  // Q fragments (B-operand): row q, k-chunk (hi*8) within kc*16
  short8 qf[2][4];
  #pragma unroll
  for (int s = 0; s < 2; ++s)
    #pragma unroll
    for (int kc = 0; kc < 4; ++kc)
      qf[s][kc] = *reinterpret_cast<const short8*>(
          qk + (size_t)(b * SEQ + q0 + wq * 64 + s * 32 + lo) * 2048 + h * 64 + kc * 16 + hi * 8);

  auto STAGE = [&](int bb, int kt) {
    #pragma unroll
    for (int i = 0; i < 2; ++i) {
      const int slot = i * 256 + tid;
      const int r = slot >> 3;
      const int c = (slot & 7) ^ (r & 7);           // inverse-swizzled source chunk
      gload16(qk + (size_t)(b * SEQ + kt + r) * 2048 + 1024 + h * 64 + c * 8,
              &sK[bb][(i * 256 + wq * 64) * 8]);
      gload16(vt + (size_t)(h * 64 + r) * 8192 + b * SEQ + kt + c * 8,
              &sVt[bb][(i * 256 + wq * 64) * 8]);
    }
  };

  f32x16 acc[2][2];
  #pragma unroll
  for (int s = 0; s < 2; ++s) { acc[s][0] = zero16(); acc[s][1] = zero16(); }
  float mst[2] = {-1e30f, -1e30f}, lst[2] = {0.f, 0.f};

  STAGE(0, 0);
  for (int t = 0; t < NTT; ++t) {
    const int cur = t & 1;
    __syncthreads();                       // staged buf[cur] ready; buf[cur^1] free
    if (t + 1 < NTT) STAGE(cur ^ 1, (t + 1) * KVB);

    // K fragments (A-operand): row kv, swizzled b128 reads
    short8 kf[2][4];
    #pragma unroll
    for (int kvb = 0; kvb < 2; ++kvb)
      #pragma unroll
      for (int kc = 0; kc < 4; ++kc) {
        const int row = kvb * 32 + lo, ch = kc * 2 + hi;
        kf[kvb][kc] = *reinterpret_cast<const short8*>(
            &sK[cur][(row * 8 + (ch ^ (row & 7))) * 8]);
      }

    short8 pa[2][4];
    #pragma unroll
    for (int s = 0; s < 2; ++s) {
      // S^T = K * Q^T : lane holds q=lo, kv rows in regs
      f32x16 st[2];
      #pragma unroll
      for (int kvb = 0; kvb < 2; ++kvb) {
        f32x16 tq = zero16();
        tq = mfma32(kf[kvb][0], qf[s][0], tq);
        tq = mfma32(kf[kvb][1], qf[s][1], tq);
        tq = mfma32(kf[kvb][2], qf[s][2], tq);
        tq = mfma32(kf[kvb][3], qf[s][3], tq);
        st[kvb] = tq;
      }
      // row max: in-register tree + one cross-half swap
      float pm = fmaxf(st[0][0], st[0][1]);
      #pragma unroll
      for (int r = 2; r < 16; ++r) pm = fmaxf(pm, st[0][r]);
      #pragma unroll
      for (int r = 0; r < 16; ++r) pm = fmaxf(pm, st[1][r]);
      pm = fmaxf(pm, __shfl_xor(pm, 32));
      // defer-max: rescale only when max grew by > 8
      if (__any(pm > mst[s] + 8.f)) {
        const float mn = fmaxf(mst[s], pm);
        const float al = __expf(mst[s] - mn);
        mst[s] = mn; lst[s] *= al;
        sBc[wq][s][lo] = al;
        asm volatile("s_waitcnt lgkmcnt(0)" ::: "memory");
        #pragma unroll
        for (int g = 0; g < 4; ++g) {
          const f32x4 a4 = *reinterpret_cast<const f32x4*>(&sBc[wq][s][g * 8 + hi * 4]);
          #pragma unroll
          for (int j = 0; j < 4; ++j) {
            acc[s][0][g * 4 + j] *= a4[j];
            acc[s][1][g * 4 + j] *= a4[j];
          }
        }
      }
      // P = exp(S - m), row sum
      #pragma unroll
      for (int kvb = 0; kvb < 2; ++kvb)
        #pragma unroll
        for (int r = 0; r < 16; ++r)
          st[kvb][r] = __expf(st[kvb][r] - mst[s]);
      {
        const f32x16 sv = st[0] + st[1];
        float sum = ((sv[0] + sv[1]) + (sv[2] + sv[3])) + ((sv[4] + sv[5]) + (sv[6] + sv[7]))
                  + ((sv[8] + sv[9]) + (sv[10] + sv[11])) + ((sv[12] + sv[13]) + (sv[14] + sv[15]));
        sum += __shfl_xor(sum, 32);
        lst[s] += sum;
      }
      // pack P -> bf16 A-fragments via cvt_pk + permlane32_swap
      #pragma unroll
      for (int kvb = 0; kvb < 2; ++kvb)
        #pragma unroll
        for (int f = 0; f < 2; ++f) {
          uint32_t wa = pkbf(st[kvb][f * 8 + 0], st[kvb][f * 8 + 1]);
          uint32_t wb = pkbf(st[kvb][f * 8 + 2], st[kvb][f * 8 + 3]);
          uint32_t wc = pkbf(st[kvb][f * 8 + 4], st[kvb][f * 8 + 5]);
          uint32_t wd = pkbf(st[kvb][f * 8 + 6], st[kvb][f * 8 + 7]);
          asm volatile("v_permlane32_swap_b32 %0, %1" : "+v"(wa), "+v"(wc));
          asm volatile("v_permlane32_swap_b32 %0, %1" : "+v"(wb), "+v"(wd));
          union { uint32_t w[4]; short8 v; } u;
          u.w[0] = wa; u.w[1] = wb; u.w[2] = wc; u.w[3] = wd;
          pa[s][kvb * 2 + f] = u.v;
        }
    }

    // O += P V  (B-operand = V^T rows d)
    #pragma unroll
    for (int db = 0; db < 2; ++db) {
      short8 vb[4];
      #pragma unroll
      for (int k4 = 0; k4 < 4; ++k4) {
        const int row = db * 32 + lo, ch = k4 * 2 + hi;
        vb[k4] = *reinterpret_cast<const short8*>(
            &sVt[cur][(row * 8 + (ch ^ (row & 7))) * 8]);
      }
      #pragma unroll
      for (int s = 0; s < 2; ++s) {
        acc[s][db] = mfma32(pa[s][0], vb[0], acc[s][db]);
        acc[s][db] = mfma32(pa[s][1], vb[1], acc[s][db]);
        acc[s][db] = mfma32(pa[s][2], vb[2], acc[s][db]);
        acc[s][db] = mfma32(pa[s][3], vb[3], acc[s][db]);
      }
    }
  }

  // epilogue: O /= l, write bf16 [8192][1024]
  #pragma unroll
  for (int s = 0; s < 2; ++s) sBc[wq][s][lo] = 1.f / lst[s];
  asm volatile("s_waitcnt lgkmcnt(0)" ::: "memory");
  #pragma unroll
  for (int s = 0; s < 2; ++s)
    #pragma unroll
    for (int g = 0; g < 4; ++g) {
      const f32x4 r4 = *reinterpret_cast<const f32x4*>(&sBc[wq][s][g * 8 + hi * 4]);
      #pragma unroll
      for (int j = 0; j < 4; ++j) {
        const int qrow = q0 + wq * 64 + s * 32 + g * 8 + hi * 4 + j;
        #pragma unroll
        for (int db = 0; db < 2; ++db)
          outp[(size_t)(b * SEQ + qrow) * EMBED + h * 64 + db * 32 + lo] =
              f2bf(acc[s][db][g * 4 + j] * r4[j]);
      }
    }
}

// ---------------- launch ----------------
extern "C" void kernel_launch(void* const* d_in, const int* in_sizes, int n_in,
                              void* d_out, int out_size, void* d_ws, size_t ws_size,
                              hipStream_t stream) {
  const float* x     = (const float*)d_in[0];
  const float* ln1_g = (const float*)d_in[1];
  const float* ln1_b = (const float*)d_in[2];
  const float* qkv_w = (const float*)d_in[3];
  const float* out_w = (const float*)d_in[4];
  const float* out_b = (const float*)d_in[5];
  const float* ln2_g = (const float*)d_in[6];
  const float* ln2_b = (const float*)d_in[7];
  const float* fc1_w = (const float*)d_in[8];
  const float* fc1_b = (const float*)d_in[9];
  const float* fc2_w = (const float*)d_in[10];
  const float* fc2_b = (const float*)d_in[11];
  float* out = (float*)d_out;
  char* ws = (char*)d_ws;

  // workspace layout (bytes)
  ushort* qkvw = (ushort*)(ws);                                   //  6291456
  ushort* outw = (ushort*)(ws + 6291456);                         //  2097152
  ushort* fc1w = (ushort*)(ws + 8388608);                         //  8388608
  ushort* fc2w = (ushort*)(ws + 16777216);                        //  8388608
  float*  x1   = (float*) (ws + 25165824);                        // 33554432
  ushort* hbuf = (ushort*)(ws + 58720256);                        // 16777216
  ushort* qkbuf= (ushort*)(ws + 75497472);                        // 33554432  [8192][2048]
  ushort* vtbuf= (ushort*)(ws + 109051904);                       // 16777216  [1024][8192]
  ushort* obuf = (ushort*)(ws + 125829120);                       // 16777216
  ushort* gbuf = qkbuf;  // gelu buf [8192][4096] reuses qk+vt+o regions (64 MiB)

  cvt_bf16_kernel<<<3072, 256, 0, stream>>>(qkv_w, qkvw, 3 * EMBED * EMBED / 4);
  cvt_bf16_kernel<<<1024, 256, 0, stream>>>(out_w, outw, EMBED * EMBED / 4);
  cvt_bf16_kernel<<<4096, 256, 0, stream>>>(fc1_w, fc1w, HIDDEN * EMBED / 4);
  cvt_bf16_kernel<<<4096, 256, 0, stream>>>(fc2_w, fc2w, EMBED * HIDDEN / 4);

  ln_kernel<<<NTOK, 256, 0, stream>>>(x, ln1_g, ln1_b, hbuf);
  // QK: [8192][2048] = hbuf * Wqk^T   (256x256 tiles, 32x8 = 256 blocks)
  gemm64<0, true><<<256, 512, 0, stream>>>(hbuf, qkvw, nullptr, nullptr,
                                           qkbuf, nullptr, NTOK, 2 * EMBED, EMBED, 32);
  // V^T: [1024][8192] = Wv * hbuf^T   (256x128 tiles, 4x64 = 256 blocks)
  gemm64<0, false><<<256, 512, 0, stream>>>(qkvw + 2048 * 1024, hbuf, nullptr, nullptr,
                                            vtbuf, nullptr, EMBED, NTOK, EMBED, 4);
  attn_kernel<<<dim3(64, 8), 256, 0, stream>>>(qkbuf, vtbuf, obuf);
  // out-proj: (256x128 tiles, 32x8 = 256 blocks)
  gemm64<1, false><<<256, 512, 0, stream>>>(obuf, outw, out_b, x,
                                            nullptr, x1, NTOK, EMBED, EMBED, 32);
  ln_kernel<<<NTOK, 256, 0, stream>>>(x1, ln2_g, ln2_b, hbuf);
  // fc1: (256x256 tiles, 32x16 = 512 blocks)
  gemm64<2, true><<<512, 512, 0, stream>>>(hbuf, fc1w, fc1_b, nullptr,
                                           gbuf, nullptr, NTOK, HIDDEN, EMBED, 32);
  // fc2: (256x128 tiles, 32x8 = 256 blocks)
  gemm64<1, false><<<256, 512, 0, stream>>>(gbuf, fc2w, fc2_b, x1,
                                            nullptr, out, NTOK, EMBED, HIDDEN, 32);
}